// Round 4
// baseline (498.819 us; speedup 1.0000x reference)
//
#include <hip/hip_runtime.h>
#include <hip/hip_bf16.h>
#include <math.h>

// Problem constants (fixed by setup_inputs)
#define NB   4
#define NSEQ 2048
#define CIN  128
#define COUT 128
#define NH   8
#define EDIM 48      // head dim*3
#define NSPLIT 2
#define KVCHUNK (NSEQ / NSPLIT)
static constexpr float kBiasEps = 1e-6f;
// fold 48^-0.5 and log2(e) into Q so softmax uses exp2 directly
static constexpr float kQScale = (float)(0.14433756729740643 * 1.4426950408889634);

typedef __attribute__((ext_vector_type(8)))  short bf16x8;
typedef __attribute__((ext_vector_type(16))) float f32x16;
typedef __attribute__((ext_vector_type(4)))  unsigned int u32x4;

__device__ inline unsigned short f2bf(float f) {
    __hip_bfloat16 h = __float2bfloat16(f);
    return *reinterpret_cast<unsigned short*>(&h);
}
__device__ inline float bf2f(unsigned short u) {
    unsigned int x = (unsigned int)u << 16;
    return __uint_as_float(x);
}
__device__ inline unsigned int cvt_pk_bf16(float lo, float hi) {
    unsigned int r;
    asm("v_cvt_pk_bf16_f32 %0, %1, %2" : "=v"(r) : "v"(lo), "v"(hi));
    return r;
}

// ---------------------------------------------------------------------------
// Transpose the four 128x128 weight matrices: Wt[i][o] = W[o][i]
__global__ __launch_bounds__(256) void transpose_w(
    const float* __restrict__ w0, const float* __restrict__ w1,
    const float* __restrict__ w2, const float* __restrict__ w3,
    float* __restrict__ wt)
{
    const float* src;
    switch (blockIdx.y) {
        case 0:  src = w0; break;
        case 1:  src = w1; break;
        case 2:  src = w2; break;
        default: src = w3; break;
    }
    float* dst = wt + (size_t)blockIdx.y * (CIN * COUT);
    const int idx = blockIdx.x * 256 + threadIdx.x;
    const int i = idx >> 7;
    const int o = idx & 127;
    dst[idx] = src[o * CIN + i];
}

// ---------------------------------------------------------------------------
// Fused projection + VN bias-norm + head split, f32 math, split-bf16 outputs.
// Q -> qh_hi/lo[bh][n][48] (scaled), K -> kh_hi/lo[bh][n][48],
// V -> vt_hi/lo[bh][e(64)][n]  (transposed for the PV MFMA B-operand).
__global__ __launch_bounds__(256) void vn_proj(
    const float* __restrict__ qin, const float* __restrict__ vin,
    const float* __restrict__ wt_all,
    const float* __restrict__ bq, const float* __restrict__ bk,
    const float* __restrict__ bv,
    unsigned short* __restrict__ qh_hi, unsigned short* __restrict__ qh_lo,
    unsigned short* __restrict__ kh_hi, unsigned short* __restrict__ kh_lo,
    unsigned short* __restrict__ vt_hi, unsigned short* __restrict__ vt_lo)
{
    const float* x; const float* wt; const float* bias;
    switch (blockIdx.y) {
        case 0:  x = qin; wt = wt_all;               bias = bq; break;
        case 1:  x = vin; wt = wt_all + CIN * COUT;  bias = bk; break;
        default: x = vin; wt = wt_all + 2*CIN*COUT;  bias = bv; break;
    }
    const int t  = threadIdx.x;
    const int nl = t >> 5;
    const int o0 = (t & 31) << 2;
    const long bn = (long)blockIdx.x * 8 + nl;      // b*NSEQ + n
    const int b = (int)(bn >> 11);
    const int n = (int)(bn & (NSEQ - 1));
    const float4* xr4 = (const float4*)(x + bn * (CIN * 3));

    float a[4][3] = {};
    #pragma unroll 2
    for (int i4 = 0; i4 < 32; ++i4) {
        const float4 x0 = xr4[i4*3 + 0];
        const float4 x1 = xr4[i4*3 + 1];
        const float4 x2 = xr4[i4*3 + 2];
        const float xt[4][3] = {
            { x0.x, x0.y, x0.z }, { x0.w, x1.x, x1.y },
            { x1.z, x1.w, x2.x }, { x2.y, x2.z, x2.w } };
        #pragma unroll
        for (int u = 0; u < 4; ++u) {
            const float4 w = *(const float4*)(wt + (size_t)(i4*4 + u) * COUT + o0);
            const float wv[4] = { w.x, w.y, w.z, w.w };
            #pragma unroll
            for (int j = 0; j < 4; ++j)
                #pragma unroll
                for (int c = 0; c < 3; ++c)
                    a[j][c] = fmaf(wv[j], xt[u][c], a[j][c]);
        }
    }
    #pragma unroll
    for (int j = 0; j < 4; ++j) {
        const int o = o0 + j;
        const float nrm = sqrtf(a[j][0]*a[j][0] + a[j][1]*a[j][1] + a[j][2]*a[j][2]);
        float f = 1.0f + bias[o] / (nrm + kBiasEps);
        const int e = (o & 15) * 3;
        const size_t bh = (size_t)b * NH + (o >> 4);
        if (blockIdx.y == 0) f *= kQScale;
        float y0 = a[j][0]*f, y1 = a[j][1]*f, y2 = a[j][2]*f;
        unsigned short h0 = f2bf(y0), h1 = f2bf(y1), h2 = f2bf(y2);
        unsigned short l0 = f2bf(y0 - bf2f(h0));
        unsigned short l1 = f2bf(y1 - bf2f(h1));
        unsigned short l2 = f2bf(y2 - bf2f(h2));
        if (blockIdx.y == 0) {
            const size_t off = (bh * NSEQ + n) * EDIM + e;
            qh_hi[off] = h0; qh_hi[off+1] = h1; qh_hi[off+2] = h2;
            qh_lo[off] = l0; qh_lo[off+1] = l1; qh_lo[off+2] = l2;
        } else if (blockIdx.y == 1) {
            const size_t off = (bh * NSEQ + n) * EDIM + e;
            kh_hi[off] = h0; kh_hi[off+1] = h1; kh_hi[off+2] = h2;
            kh_lo[off] = l0; kh_lo[off+1] = l1; kh_lo[off+2] = l2;
        } else {
            const size_t off = (bh * 64 + e) * NSEQ + n;
            vt_hi[off] = h0; vt_hi[off+NSEQ] = h1; vt_hi[off+2*NSEQ] = h2;
            vt_lo[off] = l0; vt_lo[off+NSEQ] = l1; vt_lo[off+2*NSEQ] = l2;
        }
    }
}

// ---------------------------------------------------------------------------
// MFMA flash attention, split-bf16 operands, split-KV (NSPLIT chunks).
// Wave owns 32 q rows; block = 4 waves = 128 q rows, one kv chunk.
// Writes unnormalized partial acc + (m, lsum) per q row.
// grid 1024 = 32 bh * 16 qtile * 2 chunk, XCD-swizzled. block 256.
__global__ __launch_bounds__(256, 4) void vn_attn_mfma(
    const unsigned short* __restrict__ qh_hi, const unsigned short* __restrict__ qh_lo,
    const unsigned short* __restrict__ kh_hi, const unsigned short* __restrict__ kh_lo,
    const unsigned short* __restrict__ vt_hi, const unsigned short* __restrict__ vt_lo,
    float* __restrict__ pacc, float* __restrict__ pm, float* __restrict__ pl)
{
    // XCD swizzle: 8 XCDs, 1024 blocks -> blocks sharing a bh stay on one XCD
    const int bid = blockIdx.x;
    const int swz = (bid & 7) * 128 + (bid >> 3);
    const int bh    = swz >> 5;         // [0,32)
    const int sub   = swz & 31;
    const int qt    = sub >> 1;         // [0,16)
    const int chunk = sub & 1;          // [0,NSPLIT)

    const int lane = threadIdx.x & 63;
    const int wid  = threadIdx.x >> 6;
    const int lq   = lane & 31;
    const int half = lane >> 5;
    const int q0   = qt * 128 + wid * 32;
    const int kvbase = chunk * KVCHUNK;

    // Q B-fragments (B[k=e][n=q]: lane -> q=lq, e = 16*i + 8*half + j)
    const size_t qoff = ((size_t)bh * NSEQ + q0 + lq) * EDIM + half * 8;
    const bf16x8 qf0h = *(const bf16x8*)(qh_hi + qoff);
    const bf16x8 qf1h = *(const bf16x8*)(qh_hi + qoff + 16);
    const bf16x8 qf2h = *(const bf16x8*)(qh_hi + qoff + 32);
    const bf16x8 qf0l = *(const bf16x8*)(qh_lo + qoff);
    const bf16x8 qf1l = *(const bf16x8*)(qh_lo + qoff + 16);
    const bf16x8 qf2l = *(const bf16x8*)(qh_lo + qoff + 32);

    const size_t koff = ((size_t)bh * NSEQ + lq) * EDIM + half * 8;
    const size_t voff = ((size_t)bh * 64 + lq) * NSEQ + half * 8;

    f32x16 acc0 = {}, acc1 = {};
    float m = -INFINITY, lsum = 0.0f;

    for (int kvi = 0; kvi < KVCHUNK; kvi += 32) {
        const int kv0 = kvbase + kvi;
        // K A-fragments: row kv = kv0+lq, e = 16*i + 8*half + j
        const size_t kc = koff + (size_t)kv0 * EDIM;
        const bf16x8 kf0h = *(const bf16x8*)(kh_hi + kc);
        const bf16x8 kf1h = *(const bf16x8*)(kh_hi + kc + 16);
        const bf16x8 kf2h = *(const bf16x8*)(kh_hi + kc + 32);
        const bf16x8 kf0l = *(const bf16x8*)(kh_lo + kc);
        const bf16x8 kf1l = *(const bf16x8*)(kh_lo + kc + 16);
        const bf16x8 kf2l = *(const bf16x8*)(kh_lo + kc + 32);
        // V B-fragments: e-col = 32*t + lq, kv = kv0 + 16*i + 8*half + j
        const bf16x8 vf00h = *(const bf16x8*)(vt_hi + voff + kv0);
        const bf16x8 vf01h = *(const bf16x8*)(vt_hi + voff + kv0 + 16);
        const bf16x8 vf10h = *(const bf16x8*)(vt_hi + voff + (size_t)32 * NSEQ + kv0);
        const bf16x8 vf11h = *(const bf16x8*)(vt_hi + voff + (size_t)32 * NSEQ + kv0 + 16);
        const bf16x8 vf00l = *(const bf16x8*)(vt_lo + voff + kv0);
        const bf16x8 vf01l = *(const bf16x8*)(vt_lo + voff + kv0 + 16);
        const bf16x8 vf10l = *(const bf16x8*)(vt_lo + voff + (size_t)32 * NSEQ + kv0);
        const bf16x8 vf11l = *(const bf16x8*)(vt_lo + voff + (size_t)32 * NSEQ + kv0 + 16);

        f32x16 s = {};
        __builtin_amdgcn_s_setprio(1);
        s = __builtin_amdgcn_mfma_f32_32x32x16_bf16(kf0h, qf0h, s, 0, 0, 0);
        s = __builtin_amdgcn_mfma_f32_32x32x16_bf16(kf1h, qf1h, s, 0, 0, 0);
        s = __builtin_amdgcn_mfma_f32_32x32x16_bf16(kf2h, qf2h, s, 0, 0, 0);
        s = __builtin_amdgcn_mfma_f32_32x32x16_bf16(kf0h, qf0l, s, 0, 0, 0);
        s = __builtin_amdgcn_mfma_f32_32x32x16_bf16(kf1h, qf1l, s, 0, 0, 0);
        s = __builtin_amdgcn_mfma_f32_32x32x16_bf16(kf2h, qf2l, s, 0, 0, 0);
        s = __builtin_amdgcn_mfma_f32_32x32x16_bf16(kf0l, qf0h, s, 0, 0, 0);
        s = __builtin_amdgcn_mfma_f32_32x32x16_bf16(kf1l, qf1h, s, 0, 0, 0);
        s = __builtin_amdgcn_mfma_f32_32x32x16_bf16(kf2l, qf2h, s, 0, 0, 0);
        __builtin_amdgcn_s_setprio(0);
        // lane holds s for q = lq, kv(r) = (r&3) + 8*(r>>2) + 4*half

        float mx = fmaxf(fmaxf(fmaxf(s[0], s[1]),  fmaxf(s[2],  s[3])),
                         fmaxf(fmaxf(s[4], s[5]),  fmaxf(s[6],  s[7])));
        mx = fmaxf(mx, fmaxf(fmaxf(fmaxf(s[8],  s[9]),  fmaxf(s[10], s[11])),
                             fmaxf(fmaxf(s[12], s[13]), fmaxf(s[14], s[15]))));
        mx = fmaxf(mx, __shfl_xor(mx, 32));

        if (__any(mx > m + 8.0f)) {            // defer-max: rare
            const float mn = fmaxf(m, mx);
            const float al = exp2f(m - mn);    // alpha for q = lq
            m = mn;
            lsum *= al;
            #pragma unroll
            for (int r = 0; r < 16; ++r) {
                const int qr = (r & 3) + 8 * (r >> 2) + 4 * half;
                const float ar = __shfl(al, qr);
                acc0[r] *= ar; acc1[r] *= ar;
            }
        }

        float p[16];
        float ls = 0.0f;
        #pragma unroll
        for (int r = 0; r < 16; ++r) { p[r] = exp2f(s[r] - m); ls += p[r]; }
        lsum += ls;

        // pack P (hi + residual lo) to bf16 pairs; exchange with lane^32
        unsigned int pkh[8], pkl[8], xkh[8], xkl[8];
        #pragma unroll
        for (int j = 0; j < 8; ++j) {
            const unsigned int h = cvt_pk_bf16(p[2*j], p[2*j+1]);
            pkh[j] = h;
            const float r0 = p[2*j]   - __uint_as_float(h << 16);
            const float r1 = p[2*j+1] - __uint_as_float(h & 0xffff0000u);
            pkl[j] = cvt_pk_bf16(r0, r1);
        }
        #pragma unroll
        for (int j = 0; j < 8; ++j) {
            xkh[j] = __shfl_xor(pkh[j], 32);
            xkl[j] = __shfl_xor(pkl[j], 32);
        }

        u32x4 a0h, a1h, a0l, a1l;
        if (half == 0) {
            a0h = (u32x4){pkh[0], pkh[1], xkh[0], xkh[1]};
            a1h = (u32x4){pkh[4], pkh[5], xkh[4], xkh[5]};
            a0l = (u32x4){pkl[0], pkl[1], xkl[0], xkl[1]};
            a1l = (u32x4){pkl[4], pkl[5], xkl[4], xkl[5]};
        } else {
            a0h = (u32x4){xkh[2], xkh[3], pkh[2], pkh[3]};
            a1h = (u32x4){xkh[6], xkh[7], pkh[6], pkh[7]};
            a0l = (u32x4){xkl[2], xkl[3], pkl[2], pkl[3]};
            a1l = (u32x4){xkl[6], xkl[7], pkl[6], pkl[7]};
        }
        const bf16x8 pa0h = __builtin_bit_cast(bf16x8, a0h);  // kv 0-15
        const bf16x8 pa1h = __builtin_bit_cast(bf16x8, a1h);  // kv 16-31
        const bf16x8 pa0l = __builtin_bit_cast(bf16x8, a0l);
        const bf16x8 pa1l = __builtin_bit_cast(bf16x8, a1l);

        __builtin_amdgcn_s_setprio(1);
        acc0 = __builtin_amdgcn_mfma_f32_32x32x16_bf16(pa0h, vf00h, acc0, 0, 0, 0);
        acc0 = __builtin_amdgcn_mfma_f32_32x32x16_bf16(pa1h, vf01h, acc0, 0, 0, 0);
        acc0 = __builtin_amdgcn_mfma_f32_32x32x16_bf16(pa0h, vf00l, acc0, 0, 0, 0);
        acc0 = __builtin_amdgcn_mfma_f32_32x32x16_bf16(pa1h, vf01l, acc0, 0, 0, 0);
        acc0 = __builtin_amdgcn_mfma_f32_32x32x16_bf16(pa0l, vf00h, acc0, 0, 0, 0);
        acc0 = __builtin_amdgcn_mfma_f32_32x32x16_bf16(pa1l, vf01h, acc0, 0, 0, 0);
        acc1 = __builtin_amdgcn_mfma_f32_32x32x16_bf16(pa0h, vf10h, acc1, 0, 0, 0);
        acc1 = __builtin_amdgcn_mfma_f32_32x32x16_bf16(pa1h, vf11h, acc1, 0, 0, 0);
        acc1 = __builtin_amdgcn_mfma_f32_32x32x16_bf16(pa0h, vf10l, acc1, 0, 0, 0);
        acc1 = __builtin_amdgcn_mfma_f32_32x32x16_bf16(pa1h, vf11l, acc1, 0, 0, 0);
        acc1 = __builtin_amdgcn_mfma_f32_32x32x16_bf16(pa0l, vf10h, acc1, 0, 0, 0);
        acc1 = __builtin_amdgcn_mfma_f32_32x32x16_bf16(pa1l, vf11h, acc1, 0, 0, 0);
        __builtin_amdgcn_s_setprio(0);
    }

    lsum += __shfl_xor(lsum, 32);

    // partial outputs: pacc[chunk][bh][q][48], pm/pl[chunk][bh][q]
    float* xp = pacc + (size_t)chunk * ((size_t)32 * NSEQ * EDIM)
                     + ((size_t)bh * NSEQ + q0) * EDIM;
    #pragma unroll
    for (int r = 0; r < 16; ++r) {
        const int qr = (r & 3) + 8 * (r >> 2) + 4 * half;
        xp[(size_t)qr * EDIM + lq] = acc0[r];
        if (lq < 16) xp[(size_t)qr * EDIM + 32 + lq] = acc1[r];
    }
    if (half == 0) {
        const size_t idx = (size_t)chunk * (32 * NSEQ) + (size_t)bh * NSEQ + q0 + lq;
        pm[idx] = m;
        pl[idx] = lsum;
    }
}

// ---------------------------------------------------------------------------
// Fused split-KV combine + output projection + VN bias-norm.
// out[b,n,o,c] from pacc[chunk][bh][n][e] partials. grid 1024, block 256.
__global__ __launch_bounds__(256) void vn_oproj(
    const float* __restrict__ pacc, const float* __restrict__ pm,
    const float* __restrict__ pl,
    const float* __restrict__ wt,   // Wp^T [CIN][COUT]
    const float* __restrict__ bias,
    float* __restrict__ out)
{
    const int t  = threadIdx.x;
    const int nl = t >> 5;
    const int o0 = (t & 31) << 2;
    const long bn = (long)blockIdx.x * 8 + nl;
    const int b = (int)(bn >> 11);
    const int n = (int)(bn & (NSEQ - 1));
    const size_t PACC_CHUNK = (size_t)32 * NSEQ * EDIM;
    const size_t PM_CHUNK   = (size_t)32 * NSEQ;

    float a[4][3] = {};
    for (int h = 0; h < NH; ++h) {
        const size_t row = (size_t)(b * NH + h) * NSEQ + n;
        const float m0 = pm[row], l0 = pl[row];
        const float m1 = pm[row + PM_CHUNK], l1 = pl[row + PM_CHUNK];
        const float M  = fmaxf(m0, m1);
        const float w0 = exp2f(m0 - M), w1 = exp2f(m1 - M);
        const float inv = 1.0f / (l0 * w0 + l1 * w1);
        const float s0 = w0 * inv, s1 = w1 * inv;
        const float4* a0p = (const float4*)(pacc + row * EDIM);
        const float4* a1p = (const float4*)(pacc + PACC_CHUNK + row * EDIM);
        float xv[EDIM];
        #pragma unroll
        for (int j = 0; j < 12; ++j) {
            const float4 u = a0p[j], w = a1p[j];
            xv[4*j+0] = u.x*s0 + w.x*s1;
            xv[4*j+1] = u.y*s0 + w.y*s1;
            xv[4*j+2] = u.z*s0 + w.z*s1;
            xv[4*j+3] = u.w*s0 + w.w*s1;
        }
        #pragma unroll
        for (int il = 0; il < 16; ++il) {
            const int i = h * 16 + il;
            const float4 w = *(const float4*)(wt + (size_t)i * COUT + o0);
            const float wv[4] = { w.x, w.y, w.z, w.w };
            #pragma unroll
            for (int j = 0; j < 4; ++j)
                #pragma unroll
                for (int c = 0; c < 3; ++c)
                    a[j][c] = fmaf(wv[j], xv[il*3 + c], a[j][c]);
        }
    }
    #pragma unroll
    for (int j = 0; j < 4; ++j) {
        const int o = o0 + j;
        const float nrm = sqrtf(a[j][0]*a[j][0] + a[j][1]*a[j][1] + a[j][2]*a[j][2]);
        const float f = 1.0f + bias[o] / (nrm + kBiasEps);
        float* dp = out + ((size_t)bn * COUT + o) * 3;
        dp[0] = a[j][0] * f;
        dp[1] = a[j][1] * f;
        dp[2] = a[j][2] * f;
    }
}

// ---------------------------------------------------------------------------
extern "C" void kernel_launch(void* const* d_in, const int* in_sizes, int n_in,
                              void* d_out, int out_size, void* d_ws, size_t ws_size,
                              hipStream_t stream)
{
    const float* q  = (const float*)d_in[0];
    const float* v  = (const float*)d_in[1];
    const float* Wq = (const float*)d_in[2];
    const float* bq = (const float*)d_in[3];
    const float* Wk = (const float*)d_in[4];
    const float* bk = (const float*)d_in[5];
    const float* Wv = (const float*)d_in[6];
    const float* bv = (const float*)d_in[7];
    const float* Wp = (const float*)d_in[8];
    const float* bp = (const float*)d_in[9];
    float* out = (float*)d_out;
    float* wsf = (float*)d_ws;

    const size_t WT_FLOATS = (size_t)4 * CIN * COUT;               // 65536
    const size_t QKV_ELEMS = (size_t)NB * NH * NSEQ * EDIM;        // 3145728 bf16
    const size_t VT_ELEMS  = (size_t)NB * NH * 64 * NSEQ;          // 4194304 bf16
    const size_t PACC_FLOATS = (size_t)NSPLIT * 32 * NSEQ * EDIM;  // 6291456
    const size_t PM_FLOATS   = (size_t)NSPLIT * 32 * NSEQ;         // 131072

    float* wt = wsf;
    unsigned short* qh_hi = (unsigned short*)(wsf + WT_FLOATS);
    unsigned short* qh_lo = qh_hi + QKV_ELEMS;
    unsigned short* kh_hi = qh_lo + QKV_ELEMS;
    unsigned short* kh_lo = kh_hi + QKV_ELEMS;
    unsigned short* vt_hi = kh_lo + QKV_ELEMS;
    unsigned short* vt_lo = vt_hi + VT_ELEMS;
    float* pacc = (float*)(vt_lo + VT_ELEMS);
    float* pm   = pacc + PACC_FLOATS;
    float* pl   = pm + PM_FLOATS;

    transpose_w<<<dim3(64, 4), 256, 0, stream>>>(Wq, Wk, Wv, Wp, wt);
    vn_proj<<<dim3(NB * NSEQ / 8, 3), 256, 0, stream>>>(
        q, v, wt, bq, bk, bv, qh_hi, qh_lo, kh_hi, kh_lo, vt_hi, vt_lo);
    vn_attn_mfma<<<dim3(32 * 16 * NSPLIT), 256, 0, stream>>>(
        qh_hi, qh_lo, kh_hi, kh_lo, vt_hi, vt_lo, pacc, pm, pl);
    vn_oproj<<<dim3(NB * NSEQ / 8), 256, 0, stream>>>(
        pacc, pm, pl, wt + 3 * (size_t)CIN * COUT, bp, out);
}

// Round 5
// 310.061 us; speedup vs baseline: 1.6088x; 1.6088x over previous
//
#include <hip/hip_runtime.h>
#include <hip/hip_bf16.h>
#include <math.h>

// Problem constants (fixed by setup_inputs)
#define NB   4
#define NSEQ 2048
#define CIN  128
#define COUT 128
#define NH   8
#define EDIM 48      // head dim*3
#define NSPLIT 2
#define KVCHUNK (NSEQ / NSPLIT)
static constexpr float kBiasEps = 1e-6f;
// fold 48^-0.5 and log2(e) into Q so softmax uses exp2 directly
static constexpr float kQScale = (float)(0.14433756729740643 * 1.4426950408889634);

typedef __attribute__((ext_vector_type(8)))  short bf16x8;
typedef __attribute__((ext_vector_type(16))) float f32x16;
typedef __attribute__((ext_vector_type(4)))  unsigned int u32x4;

__device__ inline unsigned short f2bf(float f) {
    __hip_bfloat16 h = __float2bfloat16(f);
    return *reinterpret_cast<unsigned short*>(&h);
}
__device__ inline float bf2f(unsigned short u) {
    unsigned int x = (unsigned int)u << 16;
    return __uint_as_float(x);
}
__device__ inline unsigned int cvt_pk_bf16(float lo, float hi) {
    unsigned int r;
    asm("v_cvt_pk_bf16_f32 %0, %1, %2" : "=v"(r) : "v"(lo), "v"(hi));
    return r;
}

// ---------------------------------------------------------------------------
// Transpose the four 128x128 weight matrices: Wt[i][o] = W[o][i]
__global__ __launch_bounds__(256) void transpose_w(
    const float* __restrict__ w0, const float* __restrict__ w1,
    const float* __restrict__ w2, const float* __restrict__ w3,
    float* __restrict__ wt)
{
    const float* src;
    switch (blockIdx.y) {
        case 0:  src = w0; break;
        case 1:  src = w1; break;
        case 2:  src = w2; break;
        default: src = w3; break;
    }
    float* dst = wt + (size_t)blockIdx.y * (CIN * COUT);
    const int idx = blockIdx.x * 256 + threadIdx.x;
    const int i = idx >> 7;
    const int o = idx & 127;
    dst[idx] = src[o * CIN + i];
}

// ---------------------------------------------------------------------------
// Fused projection + VN bias-norm + head split, f32 math, split-bf16 outputs.
// Q -> qh_hi/lo[bh][n][48] (scaled), K -> kh_hi/lo[bh][n][48],
// V -> vt_hi/lo[bh][e(64)][n]  (transposed for the PV MFMA B-operand).
__global__ __launch_bounds__(256) void vn_proj(
    const float* __restrict__ qin, const float* __restrict__ vin,
    const float* __restrict__ wt_all,
    const float* __restrict__ bq, const float* __restrict__ bk,
    const float* __restrict__ bv,
    unsigned short* __restrict__ qh_hi, unsigned short* __restrict__ qh_lo,
    unsigned short* __restrict__ kh_hi, unsigned short* __restrict__ kh_lo,
    unsigned short* __restrict__ vt_hi, unsigned short* __restrict__ vt_lo)
{
    const float* x; const float* wt; const float* bias;
    switch (blockIdx.y) {
        case 0:  x = qin; wt = wt_all;               bias = bq; break;
        case 1:  x = vin; wt = wt_all + CIN * COUT;  bias = bk; break;
        default: x = vin; wt = wt_all + 2*CIN*COUT;  bias = bv; break;
    }
    const int t  = threadIdx.x;
    const int nl = t >> 5;
    const int o0 = (t & 31) << 2;
    const long bn = (long)blockIdx.x * 8 + nl;      // b*NSEQ + n
    const int b = (int)(bn >> 11);
    const int n = (int)(bn & (NSEQ - 1));
    const float4* xr4 = (const float4*)(x + bn * (CIN * 3));

    float a[4][3] = {};
    #pragma unroll 2
    for (int i4 = 0; i4 < 32; ++i4) {
        const float4 x0 = xr4[i4*3 + 0];
        const float4 x1 = xr4[i4*3 + 1];
        const float4 x2 = xr4[i4*3 + 2];
        const float xt[4][3] = {
            { x0.x, x0.y, x0.z }, { x0.w, x1.x, x1.y },
            { x1.z, x1.w, x2.x }, { x2.y, x2.z, x2.w } };
        #pragma unroll
        for (int u = 0; u < 4; ++u) {
            const float4 w = *(const float4*)(wt + (size_t)(i4*4 + u) * COUT + o0);
            const float wv[4] = { w.x, w.y, w.z, w.w };
            #pragma unroll
            for (int j = 0; j < 4; ++j)
                #pragma unroll
                for (int c = 0; c < 3; ++c)
                    a[j][c] = fmaf(wv[j], xt[u][c], a[j][c]);
        }
    }
    #pragma unroll
    for (int j = 0; j < 4; ++j) {
        const int o = o0 + j;
        const float nrm = sqrtf(a[j][0]*a[j][0] + a[j][1]*a[j][1] + a[j][2]*a[j][2]);
        float f = 1.0f + bias[o] / (nrm + kBiasEps);
        const int e = (o & 15) * 3;
        const size_t bh = (size_t)b * NH + (o >> 4);
        if (blockIdx.y == 0) f *= kQScale;
        float y0 = a[j][0]*f, y1 = a[j][1]*f, y2 = a[j][2]*f;
        unsigned short h0 = f2bf(y0), h1 = f2bf(y1), h2 = f2bf(y2);
        unsigned short l0 = f2bf(y0 - bf2f(h0));
        unsigned short l1 = f2bf(y1 - bf2f(h1));
        unsigned short l2 = f2bf(y2 - bf2f(h2));
        if (blockIdx.y == 0) {
            const size_t off = (bh * NSEQ + n) * EDIM + e;
            qh_hi[off] = h0; qh_hi[off+1] = h1; qh_hi[off+2] = h2;
            qh_lo[off] = l0; qh_lo[off+1] = l1; qh_lo[off+2] = l2;
        } else if (blockIdx.y == 1) {
            const size_t off = (bh * NSEQ + n) * EDIM + e;
            kh_hi[off] = h0; kh_hi[off+1] = h1; kh_hi[off+2] = h2;
            kh_lo[off] = l0; kh_lo[off+1] = l1; kh_lo[off+2] = l2;
        } else {
            const size_t off = (bh * 64 + e) * NSEQ + n;
            vt_hi[off] = h0; vt_hi[off+NSEQ] = h1; vt_hi[off+2*NSEQ] = h2;
            vt_lo[off] = l0; vt_lo[off+NSEQ] = l1; vt_lo[off+2*NSEQ] = l2;
        }
    }
}

// ---------------------------------------------------------------------------
// MFMA flash attention, split-bf16 operands, split-KV (NSPLIT chunks).
// Wave owns 32 q rows; block = 4 waves = 128 q rows, one kv chunk.
// Writes unnormalized partial acc + (m, lsum) per q row.
// grid 1024 = 32 bh * 16 qtile * 2 chunk, XCD-swizzled. block 256.
// NOTE: no min-waves arg — R4's (256,4) forced VGPR=64 and spilled 1.1 GB.
__global__ __launch_bounds__(256) void vn_attn_mfma(
    const unsigned short* __restrict__ qh_hi, const unsigned short* __restrict__ qh_lo,
    const unsigned short* __restrict__ kh_hi, const unsigned short* __restrict__ kh_lo,
    const unsigned short* __restrict__ vt_hi, const unsigned short* __restrict__ vt_lo,
    float* __restrict__ pacc, float* __restrict__ pm, float* __restrict__ pl)
{
    // XCD swizzle: 8 XCDs, 1024 blocks -> blocks sharing a bh stay on one XCD
    const int bid = blockIdx.x;
    const int swz = (bid & 7) * 128 + (bid >> 3);
    const int bh    = swz >> 5;         // [0,32)
    const int sub   = swz & 31;
    const int qt    = sub >> 1;         // [0,16)
    const int chunk = sub & 1;          // [0,NSPLIT)

    const int lane = threadIdx.x & 63;
    const int wid  = threadIdx.x >> 6;
    const int lq   = lane & 31;
    const int half = lane >> 5;
    const int q0   = qt * 128 + wid * 32;
    const int kvbase = chunk * KVCHUNK;

    // Q B-fragments (B[k=e][n=q]: lane -> q=lq, e = 16*i + 8*half + j)
    const size_t qoff = ((size_t)bh * NSEQ + q0 + lq) * EDIM + half * 8;
    const bf16x8 qf0h = *(const bf16x8*)(qh_hi + qoff);
    const bf16x8 qf1h = *(const bf16x8*)(qh_hi + qoff + 16);
    const bf16x8 qf2h = *(const bf16x8*)(qh_hi + qoff + 32);
    const bf16x8 qf0l = *(const bf16x8*)(qh_lo + qoff);
    const bf16x8 qf1l = *(const bf16x8*)(qh_lo + qoff + 16);
    const bf16x8 qf2l = *(const bf16x8*)(qh_lo + qoff + 32);

    const size_t koff = ((size_t)bh * NSEQ + lq) * EDIM + half * 8;
    const size_t voff = ((size_t)bh * 64 + lq) * NSEQ + half * 8;

    f32x16 acc0 = {}, acc1 = {};
    float m = -INFINITY, lsum = 0.0f;

    for (int kvi = 0; kvi < KVCHUNK; kvi += 32) {
        const int kv0 = kvbase + kvi;
        // K A-fragments: row kv = kv0+lq, e = 16*i + 8*half + j
        const size_t kc = koff + (size_t)kv0 * EDIM;
        const bf16x8 kf0h = *(const bf16x8*)(kh_hi + kc);
        const bf16x8 kf1h = *(const bf16x8*)(kh_hi + kc + 16);
        const bf16x8 kf2h = *(const bf16x8*)(kh_hi + kc + 32);
        const bf16x8 kf0l = *(const bf16x8*)(kh_lo + kc);
        const bf16x8 kf1l = *(const bf16x8*)(kh_lo + kc + 16);
        const bf16x8 kf2l = *(const bf16x8*)(kh_lo + kc + 32);
        // V B-fragments: e-col = 32*t + lq, kv = kv0 + 16*i + 8*half + j
        const bf16x8 vf00h = *(const bf16x8*)(vt_hi + voff + kv0);
        const bf16x8 vf01h = *(const bf16x8*)(vt_hi + voff + kv0 + 16);
        const bf16x8 vf10h = *(const bf16x8*)(vt_hi + voff + (size_t)32 * NSEQ + kv0);
        const bf16x8 vf11h = *(const bf16x8*)(vt_hi + voff + (size_t)32 * NSEQ + kv0 + 16);
        const bf16x8 vf00l = *(const bf16x8*)(vt_lo + voff + kv0);
        const bf16x8 vf01l = *(const bf16x8*)(vt_lo + voff + kv0 + 16);
        const bf16x8 vf10l = *(const bf16x8*)(vt_lo + voff + (size_t)32 * NSEQ + kv0);
        const bf16x8 vf11l = *(const bf16x8*)(vt_lo + voff + (size_t)32 * NSEQ + kv0 + 16);

        f32x16 s = {};
        __builtin_amdgcn_s_setprio(1);
        s = __builtin_amdgcn_mfma_f32_32x32x16_bf16(kf0h, qf0h, s, 0, 0, 0);
        s = __builtin_amdgcn_mfma_f32_32x32x16_bf16(kf1h, qf1h, s, 0, 0, 0);
        s = __builtin_amdgcn_mfma_f32_32x32x16_bf16(kf2h, qf2h, s, 0, 0, 0);
        s = __builtin_amdgcn_mfma_f32_32x32x16_bf16(kf0h, qf0l, s, 0, 0, 0);
        s = __builtin_amdgcn_mfma_f32_32x32x16_bf16(kf1h, qf1l, s, 0, 0, 0);
        s = __builtin_amdgcn_mfma_f32_32x32x16_bf16(kf2h, qf2l, s, 0, 0, 0);
        s = __builtin_amdgcn_mfma_f32_32x32x16_bf16(kf0l, qf0h, s, 0, 0, 0);
        s = __builtin_amdgcn_mfma_f32_32x32x16_bf16(kf1l, qf1h, s, 0, 0, 0);
        s = __builtin_amdgcn_mfma_f32_32x32x16_bf16(kf2l, qf2h, s, 0, 0, 0);
        __builtin_amdgcn_s_setprio(0);
        // lane holds s for q = lq, kv(r) = (r&3) + 8*(r>>2) + 4*half

        float mx = fmaxf(fmaxf(fmaxf(s[0], s[1]),  fmaxf(s[2],  s[3])),
                         fmaxf(fmaxf(s[4], s[5]),  fmaxf(s[6],  s[7])));
        mx = fmaxf(mx, fmaxf(fmaxf(fmaxf(s[8],  s[9]),  fmaxf(s[10], s[11])),
                             fmaxf(fmaxf(s[12], s[13]), fmaxf(s[14], s[15]))));
        mx = fmaxf(mx, __shfl_xor(mx, 32));

        if (__any(mx > m + 8.0f)) {            // defer-max: rare
            const float mn = fmaxf(m, mx);
            const float al = exp2f(m - mn);    // alpha for q = lq
            m = mn;
            lsum *= al;
            #pragma unroll
            for (int r = 0; r < 16; ++r) {
                const int qr = (r & 3) + 8 * (r >> 2) + 4 * half;
                const float ar = __shfl(al, qr);
                acc0[r] *= ar; acc1[r] *= ar;
            }
        }

        float p[16];
        float ls = 0.0f;
        #pragma unroll
        for (int r = 0; r < 16; ++r) { p[r] = exp2f(s[r] - m); ls += p[r]; }
        lsum += ls;

        // pack P (hi + residual lo) to bf16 pairs; exchange with lane^32
        unsigned int pkh[8], pkl[8], xkh[8], xkl[8];
        #pragma unroll
        for (int j = 0; j < 8; ++j) {
            const unsigned int h = cvt_pk_bf16(p[2*j], p[2*j+1]);
            pkh[j] = h;
            const float r0 = p[2*j]   - __uint_as_float(h << 16);
            const float r1 = p[2*j+1] - __uint_as_float(h & 0xffff0000u);
            pkl[j] = cvt_pk_bf16(r0, r1);
        }
        #pragma unroll
        for (int j = 0; j < 8; ++j) {
            xkh[j] = __shfl_xor(pkh[j], 32);
            xkl[j] = __shfl_xor(pkl[j], 32);
        }

        u32x4 a0h, a1h, a0l, a1l;
        if (half == 0) {
            a0h = (u32x4){pkh[0], pkh[1], xkh[0], xkh[1]};
            a1h = (u32x4){pkh[4], pkh[5], xkh[4], xkh[5]};
            a0l = (u32x4){pkl[0], pkl[1], xkl[0], xkl[1]};
            a1l = (u32x4){pkl[4], pkl[5], xkl[4], xkl[5]};
        } else {
            a0h = (u32x4){xkh[2], xkh[3], pkh[2], pkh[3]};
            a1h = (u32x4){xkh[6], xkh[7], pkh[6], pkh[7]};
            a0l = (u32x4){xkl[2], xkl[3], pkl[2], pkl[3]};
            a1l = (u32x4){xkl[6], xkl[7], pkl[6], pkl[7]};
        }
        const bf16x8 pa0h = __builtin_bit_cast(bf16x8, a0h);  // kv 0-15
        const bf16x8 pa1h = __builtin_bit_cast(bf16x8, a1h);  // kv 16-31
        const bf16x8 pa0l = __builtin_bit_cast(bf16x8, a0l);
        const bf16x8 pa1l = __builtin_bit_cast(bf16x8, a1l);

        __builtin_amdgcn_s_setprio(1);
        acc0 = __builtin_amdgcn_mfma_f32_32x32x16_bf16(pa0h, vf00h, acc0, 0, 0, 0);
        acc0 = __builtin_amdgcn_mfma_f32_32x32x16_bf16(pa1h, vf01h, acc0, 0, 0, 0);
        acc0 = __builtin_amdgcn_mfma_f32_32x32x16_bf16(pa0h, vf00l, acc0, 0, 0, 0);
        acc0 = __builtin_amdgcn_mfma_f32_32x32x16_bf16(pa1h, vf01l, acc0, 0, 0, 0);
        acc0 = __builtin_amdgcn_mfma_f32_32x32x16_bf16(pa0l, vf00h, acc0, 0, 0, 0);
        acc0 = __builtin_amdgcn_mfma_f32_32x32x16_bf16(pa1l, vf01h, acc0, 0, 0, 0);
        acc1 = __builtin_amdgcn_mfma_f32_32x32x16_bf16(pa0h, vf10h, acc1, 0, 0, 0);
        acc1 = __builtin_amdgcn_mfma_f32_32x32x16_bf16(pa1h, vf11h, acc1, 0, 0, 0);
        acc1 = __builtin_amdgcn_mfma_f32_32x32x16_bf16(pa0h, vf10l, acc1, 0, 0, 0);
        acc1 = __builtin_amdgcn_mfma_f32_32x32x16_bf16(pa1h, vf11l, acc1, 0, 0, 0);
        acc1 = __builtin_amdgcn_mfma_f32_32x32x16_bf16(pa0l, vf10h, acc1, 0, 0, 0);
        acc1 = __builtin_amdgcn_mfma_f32_32x32x16_bf16(pa1l, vf11h, acc1, 0, 0, 0);
        __builtin_amdgcn_s_setprio(0);
    }

    lsum += __shfl_xor(lsum, 32);

    // partial outputs: pacc[chunk][bh][q][48], pm/pl[chunk][bh][q]
    float* xp = pacc + (size_t)chunk * ((size_t)32 * NSEQ * EDIM)
                     + ((size_t)bh * NSEQ + q0) * EDIM;
    #pragma unroll
    for (int r = 0; r < 16; ++r) {
        const int qr = (r & 3) + 8 * (r >> 2) + 4 * half;
        xp[(size_t)qr * EDIM + lq] = acc0[r];
        if (lq < 16) xp[(size_t)qr * EDIM + 32 + lq] = acc1[r];
    }
    if (half == 0) {
        const size_t idx = (size_t)chunk * (32 * NSEQ) + (size_t)bh * NSEQ + q0 + lq;
        pm[idx] = m;
        pl[idx] = lsum;
    }
}

// ---------------------------------------------------------------------------
// Fused split-KV combine + output projection + VN bias-norm.
// out[b,n,o,c] from pacc[chunk][bh][n][e] partials. grid 1024, block 256.
__global__ __launch_bounds__(256) void vn_oproj(
    const float* __restrict__ pacc, const float* __restrict__ pm,
    const float* __restrict__ pl,
    const float* __restrict__ wt,   // Wp^T [CIN][COUT]
    const float* __restrict__ bias,
    float* __restrict__ out)
{
    const int t  = threadIdx.x;
    const int nl = t >> 5;
    const int o0 = (t & 31) << 2;
    const long bn = (long)blockIdx.x * 8 + nl;
    const int b = (int)(bn >> 11);
    const int n = (int)(bn & (NSEQ - 1));
    const size_t PACC_CHUNK = (size_t)32 * NSEQ * EDIM;
    const size_t PM_CHUNK   = (size_t)32 * NSEQ;

    float a[4][3] = {};
    for (int h = 0; h < NH; ++h) {
        const size_t row = (size_t)(b * NH + h) * NSEQ + n;
        const float m0 = pm[row], l0 = pl[row];
        const float m1 = pm[row + PM_CHUNK], l1 = pl[row + PM_CHUNK];
        const float M  = fmaxf(m0, m1);
        const float w0 = exp2f(m0 - M), w1 = exp2f(m1 - M);
        const float inv = 1.0f / (l0 * w0 + l1 * w1);
        const float s0 = w0 * inv, s1 = w1 * inv;
        const float4* a0p = (const float4*)(pacc + row * EDIM);
        const float4* a1p = (const float4*)(pacc + PACC_CHUNK + row * EDIM);
        float xv[EDIM];
        #pragma unroll
        for (int j = 0; j < 12; ++j) {
            const float4 u = a0p[j], w = a1p[j];
            xv[4*j+0] = u.x*s0 + w.x*s1;
            xv[4*j+1] = u.y*s0 + w.y*s1;
            xv[4*j+2] = u.z*s0 + w.z*s1;
            xv[4*j+3] = u.w*s0 + w.w*s1;
        }
        #pragma unroll
        for (int il = 0; il < 16; ++il) {
            const int i = h * 16 + il;
            const float4 w = *(const float4*)(wt + (size_t)i * COUT + o0);
            const float wv[4] = { w.x, w.y, w.z, w.w };
            #pragma unroll
            for (int j = 0; j < 4; ++j)
                #pragma unroll
                for (int c = 0; c < 3; ++c)
                    a[j][c] = fmaf(wv[j], xv[il*3 + c], a[j][c]);
        }
    }
    #pragma unroll
    for (int j = 0; j < 4; ++j) {
        const int o = o0 + j;
        const float nrm = sqrtf(a[j][0]*a[j][0] + a[j][1]*a[j][1] + a[j][2]*a[j][2]);
        const float f = 1.0f + bias[o] / (nrm + kBiasEps);
        float* dp = out + ((size_t)bn * COUT + o) * 3;
        dp[0] = a[j][0] * f;
        dp[1] = a[j][1] * f;
        dp[2] = a[j][2] * f;
    }
}

// ---------------------------------------------------------------------------
extern "C" void kernel_launch(void* const* d_in, const int* in_sizes, int n_in,
                              void* d_out, int out_size, void* d_ws, size_t ws_size,
                              hipStream_t stream)
{
    const float* q  = (const float*)d_in[0];
    const float* v  = (const float*)d_in[1];
    const float* Wq = (const float*)d_in[2];
    const float* bq = (const float*)d_in[3];
    const float* Wk = (const float*)d_in[4];
    const float* bk = (const float*)d_in[5];
    const float* Wv = (const float*)d_in[6];
    const float* bv = (const float*)d_in[7];
    const float* Wp = (const float*)d_in[8];
    const float* bp = (const float*)d_in[9];
    float* out = (float*)d_out;
    float* wsf = (float*)d_ws;

    const size_t WT_FLOATS = (size_t)4 * CIN * COUT;               // 65536
    const size_t QKV_ELEMS = (size_t)NB * NH * NSEQ * EDIM;        // 3145728 bf16
    const size_t VT_ELEMS  = (size_t)NB * NH * 64 * NSEQ;          // 4194304 bf16
    const size_t PACC_FLOATS = (size_t)NSPLIT * 32 * NSEQ * EDIM;  // 6291456
    const size_t PM_FLOATS   = (size_t)NSPLIT * 32 * NSEQ;         // 131072

    float* wt = wsf;
    unsigned short* qh_hi = (unsigned short*)(wsf + WT_FLOATS);
    unsigned short* qh_lo = qh_hi + QKV_ELEMS;
    unsigned short* kh_hi = qh_lo + QKV_ELEMS;
    unsigned short* kh_lo = kh_hi + QKV_ELEMS;
    unsigned short* vt_hi = kh_lo + QKV_ELEMS;
    unsigned short* vt_lo = vt_hi + VT_ELEMS;
    float* pacc = (float*)(vt_lo + VT_ELEMS);
    float* pm   = pacc + PACC_FLOATS;
    float* pl   = pm + PM_FLOATS;

    transpose_w<<<dim3(64, 4), 256, 0, stream>>>(Wq, Wk, Wv, Wp, wt);
    vn_proj<<<dim3(NB * NSEQ / 8, 3), 256, 0, stream>>>(
        q, v, wt, bq, bk, bv, qh_hi, qh_lo, kh_hi, kh_lo, vt_hi, vt_lo);
    vn_attn_mfma<<<dim3(32 * 16 * NSPLIT), 256, 0, stream>>>(
        qh_hi, qh_lo, kh_hi, kh_lo, vt_hi, vt_lo, pacc, pm, pl);
    vn_oproj<<<dim3(NB * NSEQ / 8), 256, 0, stream>>>(
        pacc, pm, pl, wt + 3 * (size_t)CIN * COUT, bp, out);
}

// Round 6
// 282.094 us; speedup vs baseline: 1.7683x; 1.0991x over previous
//
#include <hip/hip_runtime.h>
#include <hip/hip_bf16.h>
#include <math.h>

// Problem constants (fixed by setup_inputs)
#define NB   4
#define NSEQ 2048
#define CIN  128
#define COUT 128
#define NH   8
#define EDIM 48      // head dim*3
#define NSPLIT 2
#define KVCHUNK (NSEQ / NSPLIT)
static constexpr float kBiasEps = 1e-6f;
// fold 48^-0.5 and log2(e) into Q so softmax uses exp2 directly
static constexpr float kQScale = (float)(0.14433756729740643 * 1.4426950408889634);

// LDS tile geometry (elements = bf16)
#define KSTRIDE 56            // 48 data + pad, 16B-multiple
#define KPLANE  (32 * KSTRIDE)        // 1792
#define VSTRIDE 40            // 32 data + pad, 16B-multiple
#define VPLANE  (64 * VSTRIDE)        // 2560
#define VBASE   (2 * KPLANE)          // 3584
#define LDS_ELEMS (VBASE + 2 * VPLANE) // 8704

typedef __attribute__((ext_vector_type(8)))  short bf16x8;
typedef __attribute__((ext_vector_type(16))) float f32x16;
typedef __attribute__((ext_vector_type(4)))  unsigned int u32x4;

__device__ inline unsigned short f2bf(float f) {
    __hip_bfloat16 h = __float2bfloat16(f);
    return *reinterpret_cast<unsigned short*>(&h);
}
__device__ inline float bf2f(unsigned short u) {
    unsigned int x = (unsigned int)u << 16;
    return __uint_as_float(x);
}
__device__ inline unsigned int cvt_pk_bf16(float lo, float hi) {
    unsigned int r;
    asm("v_cvt_pk_bf16_f32 %0, %1, %2" : "=v"(r) : "v"(lo), "v"(hi));
    return r;
}

// ---------------------------------------------------------------------------
// Transpose the four 128x128 weight matrices: Wt[i][o] = W[o][i]
__global__ __launch_bounds__(256) void transpose_w(
    const float* __restrict__ w0, const float* __restrict__ w1,
    const float* __restrict__ w2, const float* __restrict__ w3,
    float* __restrict__ wt)
{
    const float* src;
    switch (blockIdx.y) {
        case 0:  src = w0; break;
        case 1:  src = w1; break;
        case 2:  src = w2; break;
        default: src = w3; break;
    }
    float* dst = wt + (size_t)blockIdx.y * (CIN * COUT);
    const int idx = blockIdx.x * 256 + threadIdx.x;
    const int i = idx >> 7;
    const int o = idx & 127;
    dst[idx] = src[o * CIN + i];
}

// ---------------------------------------------------------------------------
// Fused projection + VN bias-norm + head split, f32 math, split-bf16 outputs.
__global__ __launch_bounds__(256) void vn_proj(
    const float* __restrict__ qin, const float* __restrict__ vin,
    const float* __restrict__ wt_all,
    const float* __restrict__ bq, const float* __restrict__ bk,
    const float* __restrict__ bv,
    unsigned short* __restrict__ qh_hi, unsigned short* __restrict__ qh_lo,
    unsigned short* __restrict__ kh_hi, unsigned short* __restrict__ kh_lo,
    unsigned short* __restrict__ vt_hi, unsigned short* __restrict__ vt_lo)
{
    const float* x; const float* wt; const float* bias;
    switch (blockIdx.y) {
        case 0:  x = qin; wt = wt_all;               bias = bq; break;
        case 1:  x = vin; wt = wt_all + CIN * COUT;  bias = bk; break;
        default: x = vin; wt = wt_all + 2*CIN*COUT;  bias = bv; break;
    }
    const int t  = threadIdx.x;
    const int nl = t >> 5;
    const int o0 = (t & 31) << 2;
    const long bn = (long)blockIdx.x * 8 + nl;      // b*NSEQ + n
    const int b = (int)(bn >> 11);
    const int n = (int)(bn & (NSEQ - 1));
    const float4* xr4 = (const float4*)(x + bn * (CIN * 3));

    float a[4][3] = {};
    #pragma unroll 2
    for (int i4 = 0; i4 < 32; ++i4) {
        const float4 x0 = xr4[i4*3 + 0];
        const float4 x1 = xr4[i4*3 + 1];
        const float4 x2 = xr4[i4*3 + 2];
        const float xt[4][3] = {
            { x0.x, x0.y, x0.z }, { x0.w, x1.x, x1.y },
            { x1.z, x1.w, x2.x }, { x2.y, x2.z, x2.w } };
        #pragma unroll
        for (int u = 0; u < 4; ++u) {
            const float4 w = *(const float4*)(wt + (size_t)(i4*4 + u) * COUT + o0);
            const float wv[4] = { w.x, w.y, w.z, w.w };
            #pragma unroll
            for (int j = 0; j < 4; ++j)
                #pragma unroll
                for (int c = 0; c < 3; ++c)
                    a[j][c] = fmaf(wv[j], xt[u][c], a[j][c]);
        }
    }
    #pragma unroll
    for (int j = 0; j < 4; ++j) {
        const int o = o0 + j;
        const float nrm = sqrtf(a[j][0]*a[j][0] + a[j][1]*a[j][1] + a[j][2]*a[j][2]);
        float f = 1.0f + bias[o] / (nrm + kBiasEps);
        const int e = (o & 15) * 3;
        const size_t bh = (size_t)b * NH + (o >> 4);
        if (blockIdx.y == 0) f *= kQScale;
        float y0 = a[j][0]*f, y1 = a[j][1]*f, y2 = a[j][2]*f;
        unsigned short h0 = f2bf(y0), h1 = f2bf(y1), h2 = f2bf(y2);
        unsigned short l0 = f2bf(y0 - bf2f(h0));
        unsigned short l1 = f2bf(y1 - bf2f(h1));
        unsigned short l2 = f2bf(y2 - bf2f(h2));
        if (blockIdx.y == 0) {
            const size_t off = (bh * NSEQ + n) * EDIM + e;
            qh_hi[off] = h0; qh_hi[off+1] = h1; qh_hi[off+2] = h2;
            qh_lo[off] = l0; qh_lo[off+1] = l1; qh_lo[off+2] = l2;
        } else if (blockIdx.y == 1) {
            const size_t off = (bh * NSEQ + n) * EDIM + e;
            kh_hi[off] = h0; kh_hi[off+1] = h1; kh_hi[off+2] = h2;
            kh_lo[off] = l0; kh_lo[off+1] = l1; kh_lo[off+2] = l2;
        } else {
            const size_t off = (bh * 64 + e) * NSEQ + n;
            vt_hi[off] = h0; vt_hi[off+NSEQ] = h1; vt_hi[off+2*NSEQ] = h2;
            vt_lo[off] = l0; vt_lo[off+NSEQ] = l1; vt_lo[off+2*NSEQ] = l2;
        }
    }
}

// ---------------------------------------------------------------------------
// MFMA flash attention, split-bf16 operands, split-KV, LDS-staged K/V tiles.
// Block = 4 waves share one (bh, chunk); each wave owns 32 q rows.
// Pipeline: load(t+1)->regs || compute(t) from LDS -> barrier -> ds_write -> barrier.
// grid 1024 = 32 bh * 16 qtile * 2 chunk, XCD-swizzled. block 256.
__global__ __launch_bounds__(256, 3) void vn_attn_mfma(
    const unsigned short* __restrict__ qh_hi, const unsigned short* __restrict__ qh_lo,
    const unsigned short* __restrict__ kh_hi, const unsigned short* __restrict__ kh_lo,
    const unsigned short* __restrict__ vt_hi, const unsigned short* __restrict__ vt_lo,
    float* __restrict__ pacc, float* __restrict__ pm, float* __restrict__ pl)
{
    __shared__ __align__(16) unsigned short lds[LDS_ELEMS];

    // XCD swizzle: blocks sharing a bh stay on one XCD
    const int bid = blockIdx.x;
    const int swz = (bid & 7) * 128 + (bid >> 3);
    const int bh    = swz >> 5;         // [0,32)
    const int sub   = swz & 31;
    const int qt    = sub >> 1;         // [0,16)
    const int chunk = sub & 1;          // [0,NSPLIT)

    const int t    = threadIdx.x;
    const int lane = t & 63;
    const int wid  = t >> 6;
    const int lq   = lane & 31;
    const int half = lane >> 5;
    const int q0   = qt * 128 + wid * 32;
    const int kvbase = chunk * KVCHUNK;

    // ---- staging descriptors: 896 16B-chunks over 256 threads (3.5 each) ----
    // g<384: K plane(hi/lo) row r seg s (6 segs/row); g>=384: V plane row r seg s (4/row)
    const unsigned short* sp[4];
    int dst[4];
    long inc[4];
    #pragma unroll
    for (int i = 0; i < 4; ++i) {
        const int g = t + i * 256;
        if (g < 384) {
            const int plane = g / 192, rc = g % 192, r = rc / 6, s = rc - r * 6;
            const unsigned short* base = plane ? kh_lo : kh_hi;
            sp[i]  = base + (size_t)bh * NSEQ * EDIM + (size_t)(kvbase + r) * EDIM + s * 8;
            dst[i] = plane * KPLANE + r * KSTRIDE + s * 8;
            inc[i] = 32 * EDIM;
        } else if (g < 896) {
            const int h = g - 384, plane = h / 256, rc = h % 256, r = rc / 4, s = rc - r * 4;
            const unsigned short* base = plane ? vt_lo : vt_hi;
            sp[i]  = base + (size_t)bh * 64 * NSEQ + (size_t)r * NSEQ + kvbase + s * 8;
            dst[i] = VBASE + plane * VPLANE + r * VSTRIDE + s * 8;
            inc[i] = 32;
        } else {           // g in [896,1024): idle slot (threads 128..255, i==3)
            sp[i] = kh_hi; dst[i] = 0; inc[i] = 0;
        }
    }
    const bool has3 = (t < 128);

    // Q B-fragments (loop-invariant): lane -> q=lq, e = 16*i + 8*half + j
    const size_t qoff = ((size_t)bh * NSEQ + q0 + lq) * EDIM + half * 8;
    const bf16x8 qf0h = *(const bf16x8*)(qh_hi + qoff);
    const bf16x8 qf1h = *(const bf16x8*)(qh_hi + qoff + 16);
    const bf16x8 qf2h = *(const bf16x8*)(qh_hi + qoff + 32);
    const bf16x8 qf0l = *(const bf16x8*)(qh_lo + qoff);
    const bf16x8 qf1l = *(const bf16x8*)(qh_lo + qoff + 16);
    const bf16x8 qf2l = *(const bf16x8*)(qh_lo + qoff + 32);

    f32x16 acc0 = {}, acc1 = {};
    float m = -INFINITY, lsum = 0.0f;

    // prologue: stage tile 0
    uint4 u0 = *(const uint4*)sp[0];
    uint4 u1 = *(const uint4*)sp[1];
    uint4 u2 = *(const uint4*)sp[2];
    uint4 u3 = has3 ? *(const uint4*)sp[3] : make_uint4(0,0,0,0);
    *(uint4*)(lds + dst[0]) = u0;
    *(uint4*)(lds + dst[1]) = u1;
    *(uint4*)(lds + dst[2]) = u2;
    if (has3) *(uint4*)(lds + dst[3]) = u3;
    __syncthreads();

    const int NT = KVCHUNK / 32;
    #pragma unroll 1
    for (int ti = 0; ti < NT; ++ti) {
        // issue next tile's global loads (hidden under compute)
        if (ti + 1 < NT) {
            sp[0] += inc[0]; sp[1] += inc[1]; sp[2] += inc[2]; sp[3] += inc[3];
            u0 = *(const uint4*)sp[0];
            u1 = *(const uint4*)sp[1];
            u2 = *(const uint4*)sp[2];
            if (has3) u3 = *(const uint4*)sp[3];
        }

        // ---- K fragments from LDS ----
        const int kb = lq * KSTRIDE + half * 8;
        const bf16x8 kf0h = *(const bf16x8*)(lds + kb);
        const bf16x8 kf1h = *(const bf16x8*)(lds + kb + 16);
        const bf16x8 kf2h = *(const bf16x8*)(lds + kb + 32);
        const bf16x8 kf0l = *(const bf16x8*)(lds + KPLANE + kb);
        const bf16x8 kf1l = *(const bf16x8*)(lds + KPLANE + kb + 16);
        const bf16x8 kf2l = *(const bf16x8*)(lds + KPLANE + kb + 32);

        f32x16 s = {};
        __builtin_amdgcn_s_setprio(1);
        s = __builtin_amdgcn_mfma_f32_32x32x16_bf16(kf0h, qf0h, s, 0, 0, 0);
        s = __builtin_amdgcn_mfma_f32_32x32x16_bf16(kf1h, qf1h, s, 0, 0, 0);
        s = __builtin_amdgcn_mfma_f32_32x32x16_bf16(kf2h, qf2h, s, 0, 0, 0);
        s = __builtin_amdgcn_mfma_f32_32x32x16_bf16(kf0h, qf0l, s, 0, 0, 0);
        s = __builtin_amdgcn_mfma_f32_32x32x16_bf16(kf1h, qf1l, s, 0, 0, 0);
        s = __builtin_amdgcn_mfma_f32_32x32x16_bf16(kf2h, qf2l, s, 0, 0, 0);
        s = __builtin_amdgcn_mfma_f32_32x32x16_bf16(kf0l, qf0h, s, 0, 0, 0);
        s = __builtin_amdgcn_mfma_f32_32x32x16_bf16(kf1l, qf1h, s, 0, 0, 0);
        s = __builtin_amdgcn_mfma_f32_32x32x16_bf16(kf2l, qf2h, s, 0, 0, 0);
        __builtin_amdgcn_s_setprio(0);
        // lane holds s for q = lq, kv(r) = (r&3) + 8*(r>>2) + 4*half

        float mx = fmaxf(fmaxf(fmaxf(s[0], s[1]),  fmaxf(s[2],  s[3])),
                         fmaxf(fmaxf(s[4], s[5]),  fmaxf(s[6],  s[7])));
        mx = fmaxf(mx, fmaxf(fmaxf(fmaxf(s[8],  s[9]),  fmaxf(s[10], s[11])),
                             fmaxf(fmaxf(s[12], s[13]), fmaxf(s[14], s[15]))));
        mx = fmaxf(mx, __shfl_xor(mx, 32));

        if (__any(mx > m + 8.0f)) {            // defer-max: rare
            const float mn = fmaxf(m, mx);
            const float al = exp2f(m - mn);    // alpha for q = lq
            m = mn;
            lsum *= al;
            #pragma unroll
            for (int r = 0; r < 16; ++r) {
                const int qr = (r & 3) + 8 * (r >> 2) + 4 * half;
                const float ar = __shfl(al, qr);
                acc0[r] *= ar; acc1[r] *= ar;
            }
        }

        float p[16];
        float ls = 0.0f;
        #pragma unroll
        for (int r = 0; r < 16; ++r) { p[r] = exp2f(s[r] - m); ls += p[r]; }
        lsum += ls;

        // pack P (hi + residual lo) to bf16 pairs; exchange with lane^32
        unsigned int pkh[8], pkl[8], xkh[8], xkl[8];
        #pragma unroll
        for (int j = 0; j < 8; ++j) {
            const unsigned int h = cvt_pk_bf16(p[2*j], p[2*j+1]);
            pkh[j] = h;
            const float r0 = p[2*j]   - __uint_as_float(h << 16);
            const float r1 = p[2*j+1] - __uint_as_float(h & 0xffff0000u);
            pkl[j] = cvt_pk_bf16(r0, r1);
        }
        #pragma unroll
        for (int j = 0; j < 8; ++j) {
            xkh[j] = __shfl_xor(pkh[j], 32);
            xkl[j] = __shfl_xor(pkl[j], 32);
        }

        u32x4 a0h, a1h, a0l, a1l;
        if (half == 0) {
            a0h = (u32x4){pkh[0], pkh[1], xkh[0], xkh[1]};
            a1h = (u32x4){pkh[4], pkh[5], xkh[4], xkh[5]};
            a0l = (u32x4){pkl[0], pkl[1], xkl[0], xkl[1]};
            a1l = (u32x4){pkl[4], pkl[5], xkl[4], xkl[5]};
        } else {
            a0h = (u32x4){xkh[2], xkh[3], pkh[2], pkh[3]};
            a1h = (u32x4){xkh[6], xkh[7], pkh[6], pkh[7]};
            a0l = (u32x4){xkl[2], xkl[3], pkl[2], pkl[3]};
            a1l = (u32x4){xkl[6], xkl[7], pkl[6], pkl[7]};
        }
        const bf16x8 pa0h = __builtin_bit_cast(bf16x8, a0h);  // kv 0-15
        const bf16x8 pa1h = __builtin_bit_cast(bf16x8, a1h);  // kv 16-31
        const bf16x8 pa0l = __builtin_bit_cast(bf16x8, a0l);
        const bf16x8 pa1l = __builtin_bit_cast(bf16x8, a1l);

        // ---- V fragments from LDS (loaded late to cap live range) ----
        const int vb0 = VBASE + lq * VSTRIDE + half * 8;           // e rows 0-31
        const int vb1 = VBASE + (32 + lq) * VSTRIDE + half * 8;    // e rows 32-63
        const bf16x8 vf00h = *(const bf16x8*)(lds + vb0);
        const bf16x8 vf01h = *(const bf16x8*)(lds + vb0 + 16);
        const bf16x8 vf00l = *(const bf16x8*)(lds + VPLANE + vb0);
        const bf16x8 vf01l = *(const bf16x8*)(lds + VPLANE + vb0 + 16);

        __builtin_amdgcn_s_setprio(1);
        acc0 = __builtin_amdgcn_mfma_f32_32x32x16_bf16(pa0h, vf00h, acc0, 0, 0, 0);
        acc0 = __builtin_amdgcn_mfma_f32_32x32x16_bf16(pa1h, vf01h, acc0, 0, 0, 0);
        acc0 = __builtin_amdgcn_mfma_f32_32x32x16_bf16(pa0h, vf00l, acc0, 0, 0, 0);
        acc0 = __builtin_amdgcn_mfma_f32_32x32x16_bf16(pa1h, vf01l, acc0, 0, 0, 0);
        acc0 = __builtin_amdgcn_mfma_f32_32x32x16_bf16(pa0l, vf00h, acc0, 0, 0, 0);
        acc0 = __builtin_amdgcn_mfma_f32_32x32x16_bf16(pa1l, vf01h, acc0, 0, 0, 0);
        __builtin_amdgcn_s_setprio(0);

        const bf16x8 vf10h = *(const bf16x8*)(lds + vb1);
        const bf16x8 vf11h = *(const bf16x8*)(lds + vb1 + 16);
        const bf16x8 vf10l = *(const bf16x8*)(lds + VPLANE + vb1);
        const bf16x8 vf11l = *(const bf16x8*)(lds + VPLANE + vb1 + 16);

        __builtin_amdgcn_s_setprio(1);
        acc1 = __builtin_amdgcn_mfma_f32_32x32x16_bf16(pa0h, vf10h, acc1, 0, 0, 0);
        acc1 = __builtin_amdgcn_mfma_f32_32x32x16_bf16(pa1h, vf11h, acc1, 0, 0, 0);
        acc1 = __builtin_amdgcn_mfma_f32_32x32x16_bf16(pa0h, vf10l, acc1, 0, 0, 0);
        acc1 = __builtin_amdgcn_mfma_f32_32x32x16_bf16(pa1h, vf11l, acc1, 0, 0, 0);
        acc1 = __builtin_amdgcn_mfma_f32_32x32x16_bf16(pa0l, vf10h, acc1, 0, 0, 0);
        acc1 = __builtin_amdgcn_mfma_f32_32x32x16_bf16(pa1l, vf11h, acc1, 0, 0, 0);
        __builtin_amdgcn_s_setprio(0);

        __syncthreads();                    // all waves done reading buf
        if (ti + 1 < NT) {                  // overwrite with next tile
            *(uint4*)(lds + dst[0]) = u0;   // (compiler waits vmcnt here)
            *(uint4*)(lds + dst[1]) = u1;
            *(uint4*)(lds + dst[2]) = u2;
            if (has3) *(uint4*)(lds + dst[3]) = u3;
            __syncthreads();                // buf ready
        }
    }

    lsum += __shfl_xor(lsum, 32);

    // partial outputs: pacc[chunk][bh][q][48], pm/pl[chunk][bh][q]
    float* xp = pacc + (size_t)chunk * ((size_t)32 * NSEQ * EDIM)
                     + ((size_t)bh * NSEQ + q0) * EDIM;
    #pragma unroll
    for (int r = 0; r < 16; ++r) {
        const int qr = (r & 3) + 8 * (r >> 2) + 4 * half;
        xp[(size_t)qr * EDIM + lq] = acc0[r];
        if (lq < 16) xp[(size_t)qr * EDIM + 32 + lq] = acc1[r];
    }
    if (half == 0) {
        const size_t idx = (size_t)chunk * (32 * NSEQ) + (size_t)bh * NSEQ + q0 + lq;
        pm[idx] = m;
        pl[idx] = lsum;
    }
}

// ---------------------------------------------------------------------------
// Fused split-KV combine + output projection + VN bias-norm.
__global__ __launch_bounds__(256) void vn_oproj(
    const float* __restrict__ pacc, const float* __restrict__ pm,
    const float* __restrict__ pl,
    const float* __restrict__ wt,   // Wp^T [CIN][COUT]
    const float* __restrict__ bias,
    float* __restrict__ out)
{
    const int t  = threadIdx.x;
    const int nl = t >> 5;
    const int o0 = (t & 31) << 2;
    const long bn = (long)blockIdx.x * 8 + nl;
    const int b = (int)(bn >> 11);
    const int n = (int)(bn & (NSEQ - 1));
    const size_t PACC_CHUNK = (size_t)32 * NSEQ * EDIM;
    const size_t PM_CHUNK   = (size_t)32 * NSEQ;

    float a[4][3] = {};
    for (int h = 0; h < NH; ++h) {
        const size_t row = (size_t)(b * NH + h) * NSEQ + n;
        const float m0 = pm[row], l0 = pl[row];
        const float m1 = pm[row + PM_CHUNK], l1 = pl[row + PM_CHUNK];
        const float M  = fmaxf(m0, m1);
        const float w0 = exp2f(m0 - M), w1 = exp2f(m1 - M);
        const float inv = 1.0f / (l0 * w0 + l1 * w1);
        const float s0 = w0 * inv, s1 = w1 * inv;
        const float4* a0p = (const float4*)(pacc + row * EDIM);
        const float4* a1p = (const float4*)(pacc + PACC_CHUNK + row * EDIM);
        float xv[EDIM];
        #pragma unroll
        for (int j = 0; j < 12; ++j) {
            const float4 u = a0p[j], w = a1p[j];
            xv[4*j+0] = u.x*s0 + w.x*s1;
            xv[4*j+1] = u.y*s0 + w.y*s1;
            xv[4*j+2] = u.z*s0 + w.z*s1;
            xv[4*j+3] = u.w*s0 + w.w*s1;
        }
        #pragma unroll
        for (int il = 0; il < 16; ++il) {
            const int i = h * 16 + il;
            const float4 w = *(const float4*)(wt + (size_t)i * COUT + o0);
            const float wv[4] = { w.x, w.y, w.z, w.w };
            #pragma unroll
            for (int j = 0; j < 4; ++j)
                #pragma unroll
                for (int c = 0; c < 3; ++c)
                    a[j][c] = fmaf(wv[j], xv[il*3 + c], a[j][c]);
        }
    }
    #pragma unroll
    for (int j = 0; j < 4; ++j) {
        const int o = o0 + j;
        const float nrm = sqrtf(a[j][0]*a[j][0] + a[j][1]*a[j][1] + a[j][2]*a[j][2]);
        const float f = 1.0f + bias[o] / (nrm + kBiasEps);
        float* dp = out + ((size_t)bn * COUT + o) * 3;
        dp[0] = a[j][0] * f;
        dp[1] = a[j][1] * f;
        dp[2] = a[j][2] * f;
    }
}

// ---------------------------------------------------------------------------
extern "C" void kernel_launch(void* const* d_in, const int* in_sizes, int n_in,
                              void* d_out, int out_size, void* d_ws, size_t ws_size,
                              hipStream_t stream)
{
    const float* q  = (const float*)d_in[0];
    const float* v  = (const float*)d_in[1];
    const float* Wq = (const float*)d_in[2];
    const float* bq = (const float*)d_in[3];
    const float* Wk = (const float*)d_in[4];
    const float* bk = (const float*)d_in[5];
    const float* Wv = (const float*)d_in[6];
    const float* bv = (const float*)d_in[7];
    const float* Wp = (const float*)d_in[8];
    const float* bp = (const float*)d_in[9];
    float* out = (float*)d_out;
    float* wsf = (float*)d_ws;

    const size_t WT_FLOATS = (size_t)4 * CIN * COUT;               // 65536
    const size_t QKV_ELEMS = (size_t)NB * NH * NSEQ * EDIM;        // 3145728 bf16
    const size_t VT_ELEMS  = (size_t)NB * NH * 64 * NSEQ;          // 4194304 bf16
    const size_t PACC_FLOATS = (size_t)NSPLIT * 32 * NSEQ * EDIM;  // 6291456
    const size_t PM_FLOATS   = (size_t)NSPLIT * 32 * NSEQ;         // 131072

    float* wt = wsf;
    unsigned short* qh_hi = (unsigned short*)(wsf + WT_FLOATS);
    unsigned short* qh_lo = qh_hi + QKV_ELEMS;
    unsigned short* kh_hi = qh_lo + QKV_ELEMS;
    unsigned short* kh_lo = kh_hi + QKV_ELEMS;
    unsigned short* vt_hi = kh_lo + QKV_ELEMS;
    unsigned short* vt_lo = vt_hi + VT_ELEMS;
    float* pacc = (float*)(vt_lo + VT_ELEMS);
    float* pm   = pacc + PACC_FLOATS;
    float* pl   = pm + PM_FLOATS;

    transpose_w<<<dim3(64, 4), 256, 0, stream>>>(Wq, Wk, Wv, Wp, wt);
    vn_proj<<<dim3(NB * NSEQ / 8, 3), 256, 0, stream>>>(
        q, v, wt, bq, bk, bv, qh_hi, qh_lo, kh_hi, kh_lo, vt_hi, vt_lo);
    vn_attn_mfma<<<dim3(32 * 16 * NSPLIT), 256, 0, stream>>>(
        qh_hi, qh_lo, kh_hi, kh_lo, vt_hi, vt_lo, pacc, pm, pl);
    vn_oproj<<<dim3(NB * NSEQ / 8), 256, 0, stream>>>(
        pacc, pm, pl, wt + 3 * (size_t)CIN * COUT, bp, out);
}

// Round 8
// 272.780 us; speedup vs baseline: 1.8286x; 1.0341x over previous
//
#include <hip/hip_runtime.h>
#include <hip/hip_bf16.h>
#include <math.h>

// Problem constants (fixed by setup_inputs)
#define NB   4
#define NSEQ 2048
#define CIN  128
#define COUT 128
#define NH   8
#define EDIM 48      // head dim*3
#define NSPLIT 2
#define KVCHUNK (NSEQ / NSPLIT)
static constexpr float kBiasEps = 1e-6f;
// fold 48^-0.5 and log2(e) into Q so softmax uses exp2 directly
static constexpr float kQScale = (float)(0.14433756729740643 * 1.4426950408889634);

// LDS tile geometry (elements = bf16). Stride 64 elems = 128B = 8 segs of 16B;
// seg slot XOR-swizzled by row (s' = s ^ (r&7)) -> conflict-free ds_read_b128.
#define KSTRIDE 64
#define KPLANE  (32 * KSTRIDE)         // 2048
#define VSTRIDE 64
#define VPLANE  (64 * VSTRIDE)         // 4096
#define VBASE   (2 * KPLANE)           // 4096
#define BUFE    (VBASE + 2 * VPLANE)   // 12288 elems = 24 KB; double-buffered

typedef __attribute__((ext_vector_type(8)))  short bf16x8;
typedef __attribute__((ext_vector_type(16))) float f32x16;
typedef __attribute__((ext_vector_type(4)))  unsigned int u32x4;

__device__ inline unsigned short f2bf(float f) {
    __hip_bfloat16 h = __float2bfloat16(f);
    return *reinterpret_cast<unsigned short*>(&h);
}
__device__ inline float bf2f(unsigned short u) {
    unsigned int x = (unsigned int)u << 16;
    return __uint_as_float(x);
}
__device__ inline unsigned int cvt_pk_bf16(float lo, float hi) {
    unsigned int r;
    asm("v_cvt_pk_bf16_f32 %0, %1, %2" : "=v"(r) : "v"(lo), "v"(hi));
    return r;
}

// ---------------------------------------------------------------------------
// Transpose the four 128x128 weight matrices: Wt[i][o] = W[o][i]
__global__ __launch_bounds__(256) void transpose_w(
    const float* __restrict__ w0, const float* __restrict__ w1,
    const float* __restrict__ w2, const float* __restrict__ w3,
    float* __restrict__ wt)
{
    const float* src;
    switch (blockIdx.y) {
        case 0:  src = w0; break;
        case 1:  src = w1; break;
        case 2:  src = w2; break;
        default: src = w3; break;
    }
    float* dst = wt + (size_t)blockIdx.y * (CIN * COUT);
    const int idx = blockIdx.x * 256 + threadIdx.x;
    const int i = idx >> 7;
    const int o = idx & 127;
    dst[idx] = src[o * CIN + i];
}

// ---------------------------------------------------------------------------
// Fused projection + VN bias-norm + head split, f32 math, split-bf16 outputs.
__global__ __launch_bounds__(256) void vn_proj(
    const float* __restrict__ qin, const float* __restrict__ vin,
    const float* __restrict__ wt_all,
    const float* __restrict__ bq, const float* __restrict__ bk,
    const float* __restrict__ bv,
    unsigned short* __restrict__ qh_hi, unsigned short* __restrict__ qh_lo,
    unsigned short* __restrict__ kh_hi, unsigned short* __restrict__ kh_lo,
    unsigned short* __restrict__ vt_hi, unsigned short* __restrict__ vt_lo)
{
    const float* x; const float* wt; const float* bias;
    switch (blockIdx.y) {
        case 0:  x = qin; wt = wt_all;               bias = bq; break;
        case 1:  x = vin; wt = wt_all + CIN * COUT;  bias = bk; break;
        default: x = vin; wt = wt_all + 2*CIN*COUT;  bias = bv; break;
    }
    const int t  = threadIdx.x;
    const int nl = t >> 5;
    const int o0 = (t & 31) << 2;
    const long bn = (long)blockIdx.x * 8 + nl;      // b*NSEQ + n
    const int b = (int)(bn >> 11);
    const int n = (int)(bn & (NSEQ - 1));
    const float4* xr4 = (const float4*)(x + bn * (CIN * 3));

    float a[4][3] = {};
    #pragma unroll 2
    for (int i4 = 0; i4 < 32; ++i4) {
        const float4 x0 = xr4[i4*3 + 0];
        const float4 x1 = xr4[i4*3 + 1];
        const float4 x2 = xr4[i4*3 + 2];
        const float xt[4][3] = {
            { x0.x, x0.y, x0.z }, { x0.w, x1.x, x1.y },
            { x1.z, x1.w, x2.x }, { x2.y, x2.z, x2.w } };
        #pragma unroll
        for (int u = 0; u < 4; ++u) {
            const float4 w = *(const float4*)(wt + (size_t)(i4*4 + u) * COUT + o0);
            const float wv[4] = { w.x, w.y, w.z, w.w };
            #pragma unroll
            for (int j = 0; j < 4; ++j)
                #pragma unroll
                for (int c = 0; c < 3; ++c)
                    a[j][c] = fmaf(wv[j], xt[u][c], a[j][c]);
        }
    }
    #pragma unroll
    for (int j = 0; j < 4; ++j) {
        const int o = o0 + j;
        const float nrm = sqrtf(a[j][0]*a[j][0] + a[j][1]*a[j][1] + a[j][2]*a[j][2]);
        float f = 1.0f + bias[o] / (nrm + kBiasEps);
        const int e = (o & 15) * 3;
        const size_t bh = (size_t)b * NH + (o >> 4);
        if (blockIdx.y == 0) f *= kQScale;
        float y0 = a[j][0]*f, y1 = a[j][1]*f, y2 = a[j][2]*f;
        unsigned short h0 = f2bf(y0), h1 = f2bf(y1), h2 = f2bf(y2);
        unsigned short l0 = f2bf(y0 - bf2f(h0));
        unsigned short l1 = f2bf(y1 - bf2f(h1));
        unsigned short l2 = f2bf(y2 - bf2f(h2));
        if (blockIdx.y == 0) {
            const size_t off = (bh * NSEQ + n) * EDIM + e;
            qh_hi[off] = h0; qh_hi[off+1] = h1; qh_hi[off+2] = h2;
            qh_lo[off] = l0; qh_lo[off+1] = l1; qh_lo[off+2] = l2;
        } else if (blockIdx.y == 1) {
            const size_t off = (bh * NSEQ + n) * EDIM + e;
            kh_hi[off] = h0; kh_hi[off+1] = h1; kh_hi[off+2] = h2;
            kh_lo[off] = l0; kh_lo[off+1] = l1; kh_lo[off+2] = l2;
        } else {
            const size_t off = (bh * 64 + e) * NSEQ + n;
            vt_hi[off] = h0; vt_hi[off+NSEQ] = h1; vt_hi[off+2*NSEQ] = h2;
            vt_lo[off] = l0; vt_lo[off+NSEQ] = l1; vt_lo[off+2*NSEQ] = l2;
        }
    }
}

// ---------------------------------------------------------------------------
// MFMA flash attention, split-bf16, split-KV, swizzled dbuf LDS staging.
// Wave owns 64 q rows (2 fragment sets); block = 4 waves = 256 q rows.
// Cross-half exchange via __shfl_xor (R3-proven datapath).
// grid 512 = 32 bh * 8 qtile * 2 chunk, XCD-swizzled. block 256.
__global__ __launch_bounds__(256, 2) void vn_attn_mfma(
    const unsigned short* __restrict__ qh_hi, const unsigned short* __restrict__ qh_lo,
    const unsigned short* __restrict__ kh_hi, const unsigned short* __restrict__ kh_lo,
    const unsigned short* __restrict__ vt_hi, const unsigned short* __restrict__ vt_lo,
    float* __restrict__ pacc, float* __restrict__ pm, float* __restrict__ pl)
{
    __shared__ __align__(16) unsigned short lds[2 * BUFE];

    // XCD swizzle (512 % 8 == 0 -> bijective): blocks sharing bh stay on one XCD
    const int bid = blockIdx.x;
    const int swz = (bid & 7) * 64 + (bid >> 3);
    const int bh    = swz >> 4;         // [0,32)
    const int sub   = swz & 15;
    const int qt    = sub >> 1;         // [0,8)
    const int chunk = sub & 1;          // [0,NSPLIT)

    const int t    = threadIdx.x;
    const int lane = t & 63;
    const int wid  = t >> 6;
    const int lq   = lane & 31;
    const int half = lane >> 5;
    const int q0   = qt * 256 + wid * 64;
    const int kvbase = chunk * KVCHUNK;

    // ---- staging descriptors: 896 16B-chunks over 256 threads (3.5 each) ----
    const unsigned short* sp[4];
    int dst[4]; int inc[4];
    #pragma unroll
    for (int i = 0; i < 4; ++i) {
        const int g = t + i * 256;
        if (g < 384) {
            const int plane = g / 192, rc = g % 192, r = rc / 6, s = rc - r * 6;
            const unsigned short* base = plane ? kh_lo : kh_hi;
            sp[i]  = base + (size_t)bh * NSEQ * EDIM + (size_t)(kvbase + r) * EDIM + s * 8;
            dst[i] = plane * KPLANE + r * KSTRIDE + ((s ^ (r & 7)) << 3);
            inc[i] = 32 * EDIM;
        } else if (g < 896) {
            const int h = g - 384, plane = h / 256, rc = h % 256, r = rc / 4, s = rc & 3;
            const unsigned short* base = plane ? vt_lo : vt_hi;
            sp[i]  = base + (size_t)bh * 64 * NSEQ + (size_t)r * NSEQ + kvbase + s * 8;
            dst[i] = VBASE + plane * VPLANE + r * VSTRIDE + ((s ^ (r & 7)) << 3);
            inc[i] = 32;
        } else {
            sp[i] = kh_hi; dst[i] = 0; inc[i] = 0;
        }
    }
    const bool has3 = (t < 128);

    // Q fragments, blocks A (q0+lq) and B (q0+32+lq); loop-invariant
    const size_t qoffA = ((size_t)bh * NSEQ + q0 + lq) * EDIM + half * 8;
    const size_t qoffB = qoffA + (size_t)32 * EDIM;
    const bf16x8 qA0h = *(const bf16x8*)(qh_hi + qoffA);
    const bf16x8 qA1h = *(const bf16x8*)(qh_hi + qoffA + 16);
    const bf16x8 qA2h = *(const bf16x8*)(qh_hi + qoffA + 32);
    const bf16x8 qA0l = *(const bf16x8*)(qh_lo + qoffA);
    const bf16x8 qA1l = *(const bf16x8*)(qh_lo + qoffA + 16);
    const bf16x8 qA2l = *(const bf16x8*)(qh_lo + qoffA + 32);
    const bf16x8 qB0h = *(const bf16x8*)(qh_hi + qoffB);
    const bf16x8 qB1h = *(const bf16x8*)(qh_hi + qoffB + 16);
    const bf16x8 qB2h = *(const bf16x8*)(qh_hi + qoffB + 32);
    const bf16x8 qB0l = *(const bf16x8*)(qh_lo + qoffB);
    const bf16x8 qB1l = *(const bf16x8*)(qh_lo + qoffB + 16);
    const bf16x8 qB2l = *(const bf16x8*)(qh_lo + qoffB + 32);

    // loop-invariant LDS read offsets (swizzled)
    const int sw = lq & 7;
    const int kb0 = lq * KSTRIDE + (((half + 0) ^ sw) << 3);
    const int kb1 = lq * KSTRIDE + (((half + 2) ^ sw) << 3);
    const int kb2 = lq * KSTRIDE + (((half + 4) ^ sw) << 3);
    const int vA0 = VBASE + lq * VSTRIDE + (((half + 0) ^ sw) << 3);
    const int vA1 = VBASE + lq * VSTRIDE + (((half + 2) ^ sw) << 3);
    const int vB0 = VBASE + (32 + lq) * VSTRIDE + (((half + 0) ^ sw) << 3);
    const int vB1 = VBASE + (32 + lq) * VSTRIDE + (((half + 2) ^ sw) << 3);

    f32x16 aA0 = {}, aA1 = {}, aB0 = {}, aB1 = {};
    float mA = -INFINITY, mB = -INFINITY, lA = 0.0f, lB = 0.0f;

    // prologue: stage tile 0 into buffer 0
    uint4 u0 = *(const uint4*)sp[0];
    uint4 u1 = *(const uint4*)sp[1];
    uint4 u2 = *(const uint4*)sp[2];
    uint4 u3 = has3 ? *(const uint4*)sp[3] : make_uint4(0,0,0,0);
    *(uint4*)(lds + dst[0]) = u0;
    *(uint4*)(lds + dst[1]) = u1;
    *(uint4*)(lds + dst[2]) = u2;
    if (has3) *(uint4*)(lds + dst[3]) = u3;
    __syncthreads();

    const int NT = KVCHUNK / 32;
    #pragma unroll 1
    for (int ti = 0; ti < NT; ++ti) {
        unsigned short* cur = lds + (ti & 1) * BUFE;
        unsigned short* nxt = lds + ((ti + 1) & 1) * BUFE;

        if (ti + 1 < NT) {   // issue next tile's global loads early
            sp[0] += inc[0]; sp[1] += inc[1]; sp[2] += inc[2]; sp[3] += inc[3];
            u0 = *(const uint4*)sp[0];
            u1 = *(const uint4*)sp[1];
            u2 = *(const uint4*)sp[2];
            if (has3) u3 = *(const uint4*)sp[3];
        }

        // ---- K fragments ----
        const bf16x8 kf0h = *(const bf16x8*)(cur + kb0);
        const bf16x8 kf1h = *(const bf16x8*)(cur + kb1);
        const bf16x8 kf2h = *(const bf16x8*)(cur + kb2);
        const bf16x8 kf0l = *(const bf16x8*)(cur + KPLANE + kb0);
        const bf16x8 kf1l = *(const bf16x8*)(cur + KPLANE + kb1);
        const bf16x8 kf2l = *(const bf16x8*)(cur + KPLANE + kb2);

        f32x16 sA = {}, sB = {};
        __builtin_amdgcn_s_setprio(1);
        sA = __builtin_amdgcn_mfma_f32_32x32x16_bf16(kf0h, qA0h, sA, 0, 0, 0);
        sA = __builtin_amdgcn_mfma_f32_32x32x16_bf16(kf1h, qA1h, sA, 0, 0, 0);
        sA = __builtin_amdgcn_mfma_f32_32x32x16_bf16(kf2h, qA2h, sA, 0, 0, 0);
        sA = __builtin_amdgcn_mfma_f32_32x32x16_bf16(kf0h, qA0l, sA, 0, 0, 0);
        sA = __builtin_amdgcn_mfma_f32_32x32x16_bf16(kf1h, qA1l, sA, 0, 0, 0);
        sA = __builtin_amdgcn_mfma_f32_32x32x16_bf16(kf2h, qA2l, sA, 0, 0, 0);
        sA = __builtin_amdgcn_mfma_f32_32x32x16_bf16(kf0l, qA0h, sA, 0, 0, 0);
        sA = __builtin_amdgcn_mfma_f32_32x32x16_bf16(kf1l, qA1h, sA, 0, 0, 0);
        sA = __builtin_amdgcn_mfma_f32_32x32x16_bf16(kf2l, qA2h, sA, 0, 0, 0);
        sB = __builtin_amdgcn_mfma_f32_32x32x16_bf16(kf0h, qB0h, sB, 0, 0, 0);
        sB = __builtin_amdgcn_mfma_f32_32x32x16_bf16(kf1h, qB1h, sB, 0, 0, 0);
        sB = __builtin_amdgcn_mfma_f32_32x32x16_bf16(kf2h, qB2h, sB, 0, 0, 0);
        sB = __builtin_amdgcn_mfma_f32_32x32x16_bf16(kf0h, qB0l, sB, 0, 0, 0);
        sB = __builtin_amdgcn_mfma_f32_32x32x16_bf16(kf1h, qB1l, sB, 0, 0, 0);
        sB = __builtin_amdgcn_mfma_f32_32x32x16_bf16(kf2h, qB2l, sB, 0, 0, 0);
        sB = __builtin_amdgcn_mfma_f32_32x32x16_bf16(kf0l, qB0h, sB, 0, 0, 0);
        sB = __builtin_amdgcn_mfma_f32_32x32x16_bf16(kf1l, qB1h, sB, 0, 0, 0);
        sB = __builtin_amdgcn_mfma_f32_32x32x16_bf16(kf2l, qB2h, sB, 0, 0, 0);
        __builtin_amdgcn_s_setprio(0);
        // lane holds s for q = lq(+32 for B), kv(r) = (r&3) + 8*(r>>2) + 4*half

        float mxA = fmaxf(fmaxf(fmaxf(sA[0], sA[1]),  fmaxf(sA[2],  sA[3])),
                          fmaxf(fmaxf(sA[4], sA[5]),  fmaxf(sA[6],  sA[7])));
        mxA = fmaxf(mxA, fmaxf(fmaxf(fmaxf(sA[8],  sA[9]),  fmaxf(sA[10], sA[11])),
                               fmaxf(fmaxf(sA[12], sA[13]), fmaxf(sA[14], sA[15]))));
        mxA = fmaxf(mxA, __shfl_xor(mxA, 32));
        float mxB = fmaxf(fmaxf(fmaxf(sB[0], sB[1]),  fmaxf(sB[2],  sB[3])),
                          fmaxf(fmaxf(sB[4], sB[5]),  fmaxf(sB[6],  sB[7])));
        mxB = fmaxf(mxB, fmaxf(fmaxf(fmaxf(sB[8],  sB[9]),  fmaxf(sB[10], sB[11])),
                               fmaxf(fmaxf(sB[12], sB[13]), fmaxf(sB[14], sB[15]))));
        mxB = fmaxf(mxB, __shfl_xor(mxB, 32));

        if (__any((mxA > mA + 8.0f) || (mxB > mB + 8.0f))) {   // defer-max: rare
            const float mnA = fmaxf(mA, mxA);
            const float alA = exp2f(mA - mnA);
            mA = mnA; lA *= alA;
            const float mnB = fmaxf(mB, mxB);
            const float alB = exp2f(mB - mnB);
            mB = mnB; lB *= alB;
            #pragma unroll
            for (int r = 0; r < 16; ++r) {
                const int qr = (r & 3) + 8 * (r >> 2) + 4 * half;
                const float arA = __shfl(alA, qr);
                const float arB = __shfl(alB, qr);
                aA0[r] *= arA; aA1[r] *= arA;
                aB0[r] *= arB; aB1[r] *= arB;
            }
        }

        // ---- softmax + pack (hi + residual lo), shfl_xor cross-half (R3) ----
        u32x4 paA0h, paA1h, paA0l, paA1l, paB0h, paB1h, paB0l, paB1l;
        {
            float p[16]; float ls = 0.0f;
            #pragma unroll
            for (int r = 0; r < 16; ++r) { p[r] = exp2f(sA[r] - mA); ls += p[r]; }
            lA += ls;
            unsigned int pkh[8], pkl[8], xkh[8], xkl[8];
            #pragma unroll
            for (int j = 0; j < 8; ++j) {
                const unsigned int h = cvt_pk_bf16(p[2*j], p[2*j+1]);
                pkh[j] = h;
                const float r0 = p[2*j]   - __uint_as_float(h << 16);
                const float r1 = p[2*j+1] - __uint_as_float(h & 0xffff0000u);
                pkl[j] = cvt_pk_bf16(r0, r1);
            }
            #pragma unroll
            for (int j = 0; j < 8; ++j) {
                xkh[j] = __shfl_xor(pkh[j], 32);
                xkl[j] = __shfl_xor(pkl[j], 32);
            }
            if (half == 0) {
                paA0h = (u32x4){pkh[0], pkh[1], xkh[0], xkh[1]};
                paA1h = (u32x4){pkh[4], pkh[5], xkh[4], xkh[5]};
                paA0l = (u32x4){pkl[0], pkl[1], xkl[0], xkl[1]};
                paA1l = (u32x4){pkl[4], pkl[5], xkl[4], xkl[5]};
            } else {
                paA0h = (u32x4){xkh[2], xkh[3], pkh[2], pkh[3]};
                paA1h = (u32x4){xkh[6], xkh[7], pkh[6], pkh[7]};
                paA0l = (u32x4){xkl[2], xkl[3], pkl[2], pkl[3]};
                paA1l = (u32x4){xkl[6], xkl[7], pkl[6], pkl[7]};
            }
        }
        {
            float p[16]; float ls = 0.0f;
            #pragma unroll
            for (int r = 0; r < 16; ++r) { p[r] = exp2f(sB[r] - mB); ls += p[r]; }
            lB += ls;
            unsigned int pkh[8], pkl[8], xkh[8], xkl[8];
            #pragma unroll
            for (int j = 0; j < 8; ++j) {
                const unsigned int h = cvt_pk_bf16(p[2*j], p[2*j+1]);
                pkh[j] = h;
                const float r0 = p[2*j]   - __uint_as_float(h << 16);
                const float r1 = p[2*j+1] - __uint_as_float(h & 0xffff0000u);
                pkl[j] = cvt_pk_bf16(r0, r1);
            }
            #pragma unroll
            for (int j = 0; j < 8; ++j) {
                xkh[j] = __shfl_xor(pkh[j], 32);
                xkl[j] = __shfl_xor(pkl[j], 32);
            }
            if (half == 0) {
                paB0h = (u32x4){pkh[0], pkh[1], xkh[0], xkh[1]};
                paB1h = (u32x4){pkh[4], pkh[5], xkh[4], xkh[5]};
                paB0l = (u32x4){pkl[0], pkl[1], xkl[0], xkl[1]};
                paB1l = (u32x4){pkl[4], pkl[5], xkl[4], xkl[5]};
            } else {
                paB0h = (u32x4){xkh[2], xkh[3], pkh[2], pkh[3]};
                paB1h = (u32x4){xkh[6], xkh[7], pkh[6], pkh[7]};
                paB0l = (u32x4){xkl[2], xkl[3], pkl[2], pkl[3]};
                paB1l = (u32x4){xkl[6], xkl[7], pkl[6], pkl[7]};
            }
        }

        // ---- PV, e-block 0 (cols 0..31) ----
        {
            const bf16x8 v0h = *(const bf16x8*)(cur + vA0);
            const bf16x8 v1h = *(const bf16x8*)(cur + vA1);
            const bf16x8 v0l = *(const bf16x8*)(cur + VPLANE + vA0);
            const bf16x8 v1l = *(const bf16x8*)(cur + VPLANE + vA1);
            __builtin_amdgcn_s_setprio(1);
            aA0 = __builtin_amdgcn_mfma_f32_32x32x16_bf16(__builtin_bit_cast(bf16x8, paA0h), v0h, aA0, 0, 0, 0);
            aA0 = __builtin_amdgcn_mfma_f32_32x32x16_bf16(__builtin_bit_cast(bf16x8, paA1h), v1h, aA0, 0, 0, 0);
            aA0 = __builtin_amdgcn_mfma_f32_32x32x16_bf16(__builtin_bit_cast(bf16x8, paA0h), v0l, aA0, 0, 0, 0);
            aA0 = __builtin_amdgcn_mfma_f32_32x32x16_bf16(__builtin_bit_cast(bf16x8, paA1h), v1l, aA0, 0, 0, 0);
            aA0 = __builtin_amdgcn_mfma_f32_32x32x16_bf16(__builtin_bit_cast(bf16x8, paA0l), v0h, aA0, 0, 0, 0);
            aA0 = __builtin_amdgcn_mfma_f32_32x32x16_bf16(__builtin_bit_cast(bf16x8, paA1l), v1h, aA0, 0, 0, 0);
            aB0 = __builtin_amdgcn_mfma_f32_32x32x16_bf16(__builtin_bit_cast(bf16x8, paB0h), v0h, aB0, 0, 0, 0);
            aB0 = __builtin_amdgcn_mfma_f32_32x32x16_bf16(__builtin_bit_cast(bf16x8, paB1h), v1h, aB0, 0, 0, 0);
            aB0 = __builtin_amdgcn_mfma_f32_32x32x16_bf16(__builtin_bit_cast(bf16x8, paB0h), v0l, aB0, 0, 0, 0);
            aB0 = __builtin_amdgcn_mfma_f32_32x32x16_bf16(__builtin_bit_cast(bf16x8, paB1h), v1l, aB0, 0, 0, 0);
            aB0 = __builtin_amdgcn_mfma_f32_32x32x16_bf16(__builtin_bit_cast(bf16x8, paB0l), v0h, aB0, 0, 0, 0);
            aB0 = __builtin_amdgcn_mfma_f32_32x32x16_bf16(__builtin_bit_cast(bf16x8, paB1l), v1h, aB0, 0, 0, 0);
            __builtin_amdgcn_s_setprio(0);
        }
        // ---- PV, e-block 1 (cols 32..63; only 32..47 stored) ----
        {
            const bf16x8 v0h = *(const bf16x8*)(cur + vB0);
            const bf16x8 v1h = *(const bf16x8*)(cur + vB1);
            const bf16x8 v0l = *(const bf16x8*)(cur + VPLANE + vB0);
            const bf16x8 v1l = *(const bf16x8*)(cur + VPLANE + vB1);
            __builtin_amdgcn_s_setprio(1);
            aA1 = __builtin_amdgcn_mfma_f32_32x32x16_bf16(__builtin_bit_cast(bf16x8, paA0h), v0h, aA1, 0, 0, 0);
            aA1 = __builtin_amdgcn_mfma_f32_32x32x16_bf16(__builtin_bit_cast(bf16x8, paA1h), v1h, aA1, 0, 0, 0);
            aA1 = __builtin_amdgcn_mfma_f32_32x32x16_bf16(__builtin_bit_cast(bf16x8, paA0h), v0l, aA1, 0, 0, 0);
            aA1 = __builtin_amdgcn_mfma_f32_32x32x16_bf16(__builtin_bit_cast(bf16x8, paA1h), v1l, aA1, 0, 0, 0);
            aA1 = __builtin_amdgcn_mfma_f32_32x32x16_bf16(__builtin_bit_cast(bf16x8, paA0l), v0h, aA1, 0, 0, 0);
            aA1 = __builtin_amdgcn_mfma_f32_32x32x16_bf16(__builtin_bit_cast(bf16x8, paA1l), v1h, aA1, 0, 0, 0);
            aB1 = __builtin_amdgcn_mfma_f32_32x32x16_bf16(__builtin_bit_cast(bf16x8, paB0h), v0h, aB1, 0, 0, 0);
            aB1 = __builtin_amdgcn_mfma_f32_32x32x16_bf16(__builtin_bit_cast(bf16x8, paB1h), v1h, aB1, 0, 0, 0);
            aB1 = __builtin_amdgcn_mfma_f32_32x32x16_bf16(__builtin_bit_cast(bf16x8, paB0h), v0l, aB1, 0, 0, 0);
            aB1 = __builtin_amdgcn_mfma_f32_32x32x16_bf16(__builtin_bit_cast(bf16x8, paB1h), v1l, aB1, 0, 0, 0);
            aB1 = __builtin_amdgcn_mfma_f32_32x32x16_bf16(__builtin_bit_cast(bf16x8, paB0l), v0h, aB1, 0, 0, 0);
            aB1 = __builtin_amdgcn_mfma_f32_32x32x16_bf16(__builtin_bit_cast(bf16x8, paB1l), v1h, aB1, 0, 0, 0);
            __builtin_amdgcn_s_setprio(0);
        }

        if (ti + 1 < NT) {
            // write next tile to the other buffer; reads of nxt finished
            // before the barrier that ended iteration ti-1
            *(uint4*)(nxt + dst[0]) = u0;
            *(uint4*)(nxt + dst[1]) = u1;
            *(uint4*)(nxt + dst[2]) = u2;
            if (has3) *(uint4*)(nxt + dst[3]) = u3;
            __syncthreads();
        }
    }

    lA += __shfl_xor(lA, 32);
    lB += __shfl_xor(lB, 32);

    // partial outputs: pacc[chunk][bh][q][48], pm/pl[chunk][bh][q]
    float* xpA = pacc + (size_t)chunk * ((size_t)32 * NSEQ * EDIM)
                      + ((size_t)bh * NSEQ + q0) * EDIM;
    float* xpB = xpA + (size_t)32 * EDIM;
    #pragma unroll
    for (int r = 0; r < 16; ++r) {
        const int qr = (r & 3) + 8 * (r >> 2) + 4 * half;
        xpA[(size_t)qr * EDIM + lq] = aA0[r];
        xpB[(size_t)qr * EDIM + lq] = aB0[r];
        if (lq < 16) {
            xpA[(size_t)qr * EDIM + 32 + lq] = aA1[r];
            xpB[(size_t)qr * EDIM + 32 + lq] = aB1[r];
        }
    }
    if (half == 0) {
        const size_t idx = (size_t)chunk * (32 * NSEQ) + (size_t)bh * NSEQ + q0 + lq;
        pm[idx] = mA;       pl[idx] = lA;
        pm[idx + 32] = mB;  pl[idx + 32] = lB;
    }
}

// ---------------------------------------------------------------------------
// Fused split-KV combine + output projection + VN bias-norm.
__global__ __launch_bounds__(256) void vn_oproj(
    const float* __restrict__ pacc, const float* __restrict__ pm,
    const float* __restrict__ pl,
    const float* __restrict__ wt,   // Wp^T [CIN][COUT]
    const float* __restrict__ bias,
    float* __restrict__ out)
{
    const int t  = threadIdx.x;
    const int nl = t >> 5;
    const int o0 = (t & 31) << 2;
    const long bn = (long)blockIdx.x * 8 + nl;
    const int b = (int)(bn >> 11);
    const int n = (int)(bn & (NSEQ - 1));
    const size_t PACC_CHUNK = (size_t)32 * NSEQ * EDIM;
    const size_t PM_CHUNK   = (size_t)32 * NSEQ;

    float a[4][3] = {};
    for (int h = 0; h < NH; ++h) {
        const size_t row = (size_t)(b * NH + h) * NSEQ + n;
        const float m0 = pm[row], l0 = pl[row];
        const float m1 = pm[row + PM_CHUNK], l1 = pl[row + PM_CHUNK];
        const float M  = fmaxf(m0, m1);
        const float w0 = exp2f(m0 - M), w1 = exp2f(m1 - M);
        const float inv = 1.0f / (l0 * w0 + l1 * w1);
        const float s0 = w0 * inv, s1 = w1 * inv;
        const float4* a0p = (const float4*)(pacc + row * EDIM);
        const float4* a1p = (const float4*)(pacc + PACC_CHUNK + row * EDIM);
        float xv[EDIM];
        #pragma unroll
        for (int j = 0; j < 12; ++j) {
            const float4 u = a0p[j], w = a1p[j];
            xv[4*j+0] = u.x*s0 + w.x*s1;
            xv[4*j+1] = u.y*s0 + w.y*s1;
            xv[4*j+2] = u.z*s0 + w.z*s1;
            xv[4*j+3] = u.w*s0 + w.w*s1;
        }
        #pragma unroll
        for (int il = 0; il < 16; ++il) {
            const int i = h * 16 + il;
            const float4 w = *(const float4*)(wt + (size_t)i * COUT + o0);
            const float wv[4] = { w.x, w.y, w.z, w.w };
            #pragma unroll
            for (int j = 0; j < 4; ++j)
                #pragma unroll
                for (int c = 0; c < 3; ++c)
                    a[j][c] = fmaf(wv[j], xv[il*3 + c], a[j][c]);
        }
    }
    #pragma unroll
    for (int j = 0; j < 4; ++j) {
        const int o = o0 + j;
        const float nrm = sqrtf(a[j][0]*a[j][0] + a[j][1]*a[j][1] + a[j][2]*a[j][2]);
        const float f = 1.0f + bias[o] / (nrm + kBiasEps);
        float* dp = out + ((size_t)bn * COUT + o) * 3;
        dp[0] = a[j][0] * f;
        dp[1] = a[j][1] * f;
        dp[2] = a[j][2] * f;
    }
}

// ---------------------------------------------------------------------------
extern "C" void kernel_launch(void* const* d_in, const int* in_sizes, int n_in,
                              void* d_out, int out_size, void* d_ws, size_t ws_size,
                              hipStream_t stream)
{
    const float* q  = (const float*)d_in[0];
    const float* v  = (const float*)d_in[1];
    const float* Wq = (const float*)d_in[2];
    const float* bq = (const float*)d_in[3];
    const float* Wk = (const float*)d_in[4];
    const float* bk = (const float*)d_in[5];
    const float* Wv = (const float*)d_in[6];
    const float* bv = (const float*)d_in[7];
    const float* Wp = (const float*)d_in[8];
    const float* bp = (const float*)d_in[9];
    float* out = (float*)d_out;
    float* wsf = (float*)d_ws;

    const size_t WT_FLOATS = (size_t)4 * CIN * COUT;               // 65536
    const size_t QKV_ELEMS = (size_t)NB * NH * NSEQ * EDIM;        // 3145728 bf16
    const size_t VT_ELEMS  = (size_t)NB * NH * 64 * NSEQ;          // 4194304 bf16
    const size_t PACC_FLOATS = (size_t)NSPLIT * 32 * NSEQ * EDIM;  // 6291456
    const size_t PM_FLOATS   = (size_t)NSPLIT * 32 * NSEQ;         // 131072

    float* wt = wsf;
    unsigned short* qh_hi = (unsigned short*)(wsf + WT_FLOATS);
    unsigned short* qh_lo = qh_hi + QKV_ELEMS;
    unsigned short* kh_hi = qh_lo + QKV_ELEMS;
    unsigned short* kh_lo = kh_hi + QKV_ELEMS;
    unsigned short* vt_hi = kh_lo + QKV_ELEMS;
    unsigned short* vt_lo = vt_hi + VT_ELEMS;
    float* pacc = (float*)(vt_lo + VT_ELEMS);
    float* pm   = pacc + PACC_FLOATS;
    float* pl   = pm + PM_FLOATS;

    transpose_w<<<dim3(64, 4), 256, 0, stream>>>(Wq, Wk, Wv, Wp, wt);
    vn_proj<<<dim3(NB * NSEQ / 8, 3), 256, 0, stream>>>(
        q, v, wt, bq, bk, bv, qh_hi, qh_lo, kh_hi, kh_lo, vt_hi, vt_lo);
    vn_attn_mfma<<<dim3(32 * 8 * NSPLIT), 256, 0, stream>>>(
        qh_hi, qh_lo, kh_hi, kh_lo, vt_hi, vt_lo, pacc, pm, pl);
    vn_oproj<<<dim3(NB * NSEQ / 8), 256, 0, stream>>>(
        pacc, pm, pl, wt + 3 * (size_t)CIN * COUT, bp, out);
}